// Round 12
// baseline (281.076 us; speedup 1.0000x reference)
//
#include <hip/hip_runtime.h>
#include <math.h>
#include <stdint.h>

#define SCALEQ 0.125f

typedef __bf16 bf16_t;
typedef __bf16 bf16x8 __attribute__((ext_vector_type(8)));
typedef float f32x4 __attribute__((ext_vector_type(4)));

// global -> LDS async copy, 16B per lane. LDS dest is wave-uniform base + lane*16.
#define GLOAD_LDS16(gsrc, ldst)                                                   \
  __builtin_amdgcn_global_load_lds(                                               \
      (const __attribute__((address_space(1))) void*)(uintptr_t)(const void*)(gsrc), \
      (__attribute__((address_space(3))) void*)(uintptr_t)(void*)(ldst), 16, 0, 0)

// XCD-chunked bijective block swizzle (grid total must be %8==0).
__device__ __forceinline__ int3 xswz3() {
  const int nx = gridDim.x, ny = gridDim.y;
  int lin = (blockIdx.z * ny + blockIdx.y) * nx + blockIdx.x;
  const int n = nx * ny * gridDim.z;
  int work = (lin & 7) * (n >> 3) + (lin >> 3);
  int3 r;
  r.x = work % nx; work /= nx;
  r.y = work % ny; r.z = work / ny;
  return r;
}

// ---------------- bf16 MFMA GEMM core (128x128 tile, 4 waves, BK=64) ----------------
// Rule-#21 XOR swizzle: linear LDS dest, per-lane global SOURCE chunk permuted,
// reads apply the same involution (verified: SQ_LDS_BANK_CONFLICT == 0).
__device__ __forceinline__ void mm_bf16(const bf16_t* __restrict__ A, int lda,
                                        const bf16_t* __restrict__ B, int ldb,
                                        int K, int m0, int n0,
                                        bf16_t* As, bf16_t* Bs, f32x4 (&acc)[4][4]) {
  const int tid = threadIdx.x, lane = tid & 63, w = tid >> 6;
  const int wr = (w >> 1) * 64, wc = (w & 1) * 64;
  const int fr = lane & 15, fq = lane >> 4;
  const int c8 = (((lane & 7) ^ ((lane >> 3) & 7)) * 8);   // swizzled source chunk
  for (int kt = 0; kt < K; kt += 64) {
    __syncthreads();
#pragma unroll
    for (int t = 0; t < 4; ++t) {
      const int rl = t * 32 + w * 8 + (lane >> 3);
      GLOAD_LDS16(A + (size_t)(m0 + rl) * lda + kt + c8, As + (t * 32 + w * 8) * 64);
      GLOAD_LDS16(B + (size_t)(n0 + rl) * ldb + kt + c8, Bs + (t * 32 + w * 8) * 64);
    }
    __syncthreads();
#pragma unroll
    for (int ks = 0; ks < 2; ++ks) {
      bf16x8 af[4], bfv[4];
      const int ch = (((ks * 4 + fq) ^ (fr & 7)) << 3);
#pragma unroll
      for (int mf = 0; mf < 4; ++mf)
        af[mf] = *(const bf16x8*)(As + (wr + mf * 16 + fr) * 64 + ch);
#pragma unroll
      for (int nf = 0; nf < 4; ++nf)
        bfv[nf] = *(const bf16x8*)(Bs + (wc + nf * 16 + fr) * 64 + ch);
#pragma unroll
      for (int mf = 0; mf < 4; ++mf)
#pragma unroll
        for (int nf = 0; nf < 4; ++nf)
          acc[mf][nf] = __builtin_amdgcn_mfma_f32_16x16x32_bf16(af[mf], bfv[nf], acc[mf][nf], 0, 0, 0);
    }
  }
}

#define MM_PROLOGUE()                                  \
  __shared__ __align__(16) bf16_t As[128 * 64];        \
  __shared__ __align__(16) bf16_t Bs[128 * 64];        \
  f32x4 acc[4][4];                                     \
  _Pragma("unroll") for (int i_ = 0; i_ < 4; ++i_)     \
  _Pragma("unroll") for (int j_ = 0; j_ < 4; ++j_) acc[i_][j_] = (f32x4)0.0f;

#define MM_EPI_SETUP(M0, N0)                                   \
  const int lane = threadIdx.x & 63, w = threadIdx.x >> 6;     \
  const int fr = lane & 15, fq = lane >> 4;                    \
  const int mb = (M0) + (w >> 1) * 64, nb = (N0) + (w & 1) * 64;

// ---------------- GEMM kernels ----------------
__global__ __launch_bounds__(256) void k_qkv(const bf16_t* __restrict__ xb, const bf16_t* __restrict__ wb,
                                             bf16_t* __restrict__ qb, bf16_t* __restrict__ kb,
                                             bf16_t* __restrict__ vT) {
  MM_PROLOGUE();
  const int3 bi = xswz3();
  const int m0 = bi.y * 128, n0 = bi.x * 128;
  mm_bf16(xb, 512, wb, 512, 512, m0, n0, As, Bs, acc);
  MM_EPI_SETUP(m0, n0);
#pragma unroll
  for (int mf = 0; mf < 4; ++mf)
#pragma unroll
    for (int nf = 0; nf < 4; ++nf) {
      const int n = nb + nf * 16 + fr;
      const int which = n >> 9, hd = (n >> 6) & 7, d = n & 63;
      const int m_ = mb + mf * 16 + fq * 4;
      const int b = m_ >> 10, tok0 = m_ & 1023;
      if (which == 2) {
        union { ushort4 u; bf16_t q[4]; } pk;
#pragma unroll
        for (int r = 0; r < 4; ++r) pk.q[r] = (bf16_t)acc[mf][nf][r];
        *(ushort4*)(vT + (((size_t)b * 8 + hd) * 64 + d) * 1024 + tok0) = pk.u;
      } else {
        bf16_t* dst = which ? kb : qb;
        const float sc = which ? 1.f : SCALEQ;
#pragma unroll
        for (int r = 0; r < 4; ++r)
          dst[(((size_t)b * 8 + hd) * 1024 + tok0 + r) * 64 + d] = (bf16_t)(acc[mf][nf][r] * sc);
      }
    }
}

// 1536 blocks = 6/CU: force 6-block residency (VGPR cap 85) to kill the tail wave.
__global__ __launch_bounds__(256, 6) void k_wh(const bf16_t* __restrict__ xb, const bf16_t* __restrict__ gatw,
                                               const float* __restrict__ gWb, bf16_t* __restrict__ WhT) {
  MM_PROLOGUE();
  const int3 bi = xswz3();
  const int m0 = bi.y * 128, n0 = bi.x * 128, l = bi.z;
  const bf16_t* Wl = gatw + (size_t)l * 524288;
  const float* Wb = gWb + l * 1024;
  bf16_t* out = WhT + (size_t)l * 8388608;
  mm_bf16(xb, 512, Wl, 512, 512, m0, n0, As, Bs, acc);
  MM_EPI_SETUP(m0, n0);
#pragma unroll
  for (int mf = 0; mf < 4; ++mf)
#pragma unroll
    for (int nf = 0; nf < 4; ++nf) {
      const int h = nb + nf * 16 + fr;
      const float bias = Wb[h];
      const int m_ = mb + mf * 16 + fq * 4;
      const int b = m_ >> 10, ml = m_ & 1023;
      union { ushort4 u; bf16_t q[4]; } pk;
#pragma unroll
      for (int r = 0; r < 4; ++r) pk.q[r] = (bf16_t)(acc[mf][nf][r] + bias);
      *(ushort4*)(out + (((size_t)b << 10) + h) * 1024 + ml) = pk.u;
    }
}

// hh = elu(att_lb @ Wh_lb). Fused mode (wvo != nullptr): write per-block eo row-dot
// PARTIALS to peo[2][24][8][1024] (plain stores, no atomics); k_eored reduces.
__global__ __launch_bounds__(256, 6) void k_hhat(const bf16_t* __restrict__ att, const bf16_t* __restrict__ WhT,
                                                 bf16_t* __restrict__ hh, int ldh,
                                                 const float* __restrict__ wvo, float* __restrict__ peo) {
  MM_PROLOGUE();
  const int3 bi = xswz3();
  const int m0 = bi.y * 128, n0 = bi.x * 128;
  const int prob = bi.z;                 // l*8 + b
  const int l = prob >> 3, bz = prob & 7;
  const size_t off = ((size_t)prob) << 20;
  mm_bf16(att + off, 1024, WhT + off, 1024, 1024, m0, n0, As, Bs, acc);
  MM_EPI_SETUP(m0, n0);
  if (wvo != nullptr) {
    float w1[4], w2[4];
#pragma unroll
    for (int nf = 0; nf < 4; ++nf) {
      const int n = nb + nf * 16 + fr;
      w1[nf] = wvo[l * 1024 + n];
      w2[nf] = wvo[3072 + l * 1024 + n];
    }
    float* p1 = peo + ((size_t)prob * 8 + bi.x) * 1024;
    float* p2 = p1 + 196608;             // 24*8*1024
#pragma unroll
    for (int mf = 0; mf < 4; ++mf)
#pragma unroll
      for (int r = 0; r < 4; ++r) {
        float s1 = 0.f, s2 = 0.f;
#pragma unroll
        for (int nf = 0; nf < 4; ++nf) {
          float v = acc[mf][nf][r];
          v = v > 0.f ? v : (__expf(v) - 1.f);
          s1 = fmaf(v, w1[nf], s1);
          s2 = fmaf(v, w2[nf], s2);
        }
        s1 += __shfl_xor(s1, 1); s1 += __shfl_xor(s1, 2); s1 += __shfl_xor(s1, 4); s1 += __shfl_xor(s1, 8);
        s2 += __shfl_xor(s2, 1); s2 += __shfl_xor(s2, 2); s2 += __shfl_xor(s2, 4); s2 += __shfl_xor(s2, 8);
        if (fr == 0) {
          const int rowloc = mb + mf * 16 + fq * 4 + r;   // 0..1023 (mb local in big path)
          p1[rowloc] = s1;
          p2[rowloc] = s2;
        }
      }
  } else {
#pragma unroll
    for (int mf = 0; mf < 4; ++mf)
#pragma unroll
      for (int nf = 0; nf < 4; ++nf) {
        const int n = nb + nf * 16 + fr;
#pragma unroll
        for (int r = 0; r < 4; ++r) {
          const int m = mb + mf * 16 + fq * 4 + r;
          float v = acc[mf][nf][r];
          v = v > 0.f ? v : (__expf(v) - 1.f);
          hh[(size_t)((bz << 10) + m) * ldh + l * 1024 + n] = (bf16_t)v;
        }
      }
  }
}

// reduce peo partials -> eo1/eo2 (raw sums; constants added in k_mask)
__global__ __launch_bounds__(256) void k_eored(const float* __restrict__ peo,
                                               float* __restrict__ eo1, float* __restrict__ eo2) {
  const int m = blockIdx.x * 256 + threadIdx.x;   // 0..8191
  const int b = m >> 10, r = m & 1023;
  float s1 = 0.f, s2 = 0.f;
#pragma unroll
  for (int l = 0; l < 3; ++l)
#pragma unroll
    for (int s = 0; s < 8; ++s) {
      const size_t idx = (((size_t)(l * 8 + b)) * 8 + s) * 1024 + r;
      s1 += peo[idx];
      s2 += peo[196608 + idx];
    }
  eo1[m] = s1;
  eo2[m] = s2;
}

__global__ __launch_bounds__(256) void k_lin(const bf16_t* __restrict__ A, int lda,
                                             const bf16_t* __restrict__ B, int K,
                                             const float* __restrict__ bias, float* __restrict__ out) {
  MM_PROLOGUE();
  const int3 bi = xswz3();
  const int m0 = bi.y * 128, n0 = bi.x * 128;
  mm_bf16(A, lda, B, K, K, m0, n0, As, Bs, acc);
  MM_EPI_SETUP(m0, n0);
#pragma unroll
  for (int mf = 0; mf < 4; ++mf)
#pragma unroll
    for (int nf = 0; nf < 4; ++nf) {
      const int n = nb + nf * 16 + fr;
#pragma unroll
      for (int r = 0; r < 4; ++r) {
        const int m = mb + mf * 16 + fq * 4 + r;
        out[(size_t)m * 512 + n] = acc[mf][nf][r] + bias[n];
      }
    }
}

// fallback: Who (+)= hh @ out_W[:, l*1024:+1024].T (bias folded at l==0)
__global__ __launch_bounds__(256) void k_who_acc(const bf16_t* __restrict__ hh, const bf16_t* __restrict__ Wl,
                                                 const float* __restrict__ Wb, float* __restrict__ Who, int l) {
  MM_PROLOGUE();
  const int m0 = blockIdx.y * 128, n0 = blockIdx.x * 128;
  mm_bf16(hh, 1024, Wl, 3072, 1024, m0, n0, As, Bs, acc);
  MM_EPI_SETUP(m0, n0);
#pragma unroll
  for (int mf = 0; mf < 4; ++mf)
#pragma unroll
    for (int nf = 0; nf < 4; ++nf) {
      const int n = nb + nf * 16 + fr;
#pragma unroll
      for (int r = 0; r < 4; ++r) {
        const int m = mb + mf * 16 + fq * 4 + r;
        const size_t idx = (size_t)m * 512 + n;
        Who[idx] = acc[mf][nf][r] + (l == 0 ? Wb[n] : Who[idx]);
      }
    }
}

// ---------------- fused casts f32 -> bf16 (5 segments) ----------------
__global__ __launch_bounds__(256) void k_cast5(const float* __restrict__ s0, bf16_t* __restrict__ d0, int c0,
                                               const float* __restrict__ s1, bf16_t* __restrict__ d1, int c1,
                                               const float* __restrict__ s2, bf16_t* __restrict__ d2, int c2,
                                               const float* __restrict__ s3, bf16_t* __restrict__ d3, int c3,
                                               const float* __restrict__ s4, bf16_t* __restrict__ d4, int c4) {
  int i = blockIdx.x * 256 + threadIdx.x;
  const float* src; bf16_t* dst; int j;
  if (i < c0)      { src = s0; dst = d0; j = i; }
  else if (i < c1) { src = s1; dst = d1; j = i - c0; }
  else if (i < c2) { src = s2; dst = d2; j = i - c1; }
  else if (i < c3) { src = s3; dst = d3; j = i - c2; }
  else if (i < c4) { src = s4; dst = d4; j = i - c3; }
  else return;
  float4 v = ((const float4*)src)[j];
  union { ushort4 u; bf16_t b[4]; } p;
  p.b[0] = (bf16_t)v.x; p.b[1] = (bf16_t)v.y; p.b[2] = (bf16_t)v.z; p.b[3] = (bf16_t)v.w;
  ((ushort4*)dst)[j] = p.u;
}

// ---------------- algebraic e1/e2 (gat layers) ----------------
__global__ __launch_bounds__(256) void k_wvec(const bf16_t* __restrict__ gatwb,
                                              const float* __restrict__ gWb,
                                              const float* __restrict__ ai, const float* __restrict__ aib,
                                              const float* __restrict__ aj, const float* __restrict__ ajb,
                                              float* __restrict__ wv, float* __restrict__ con) {
  __shared__ float sred[4][64];
  __shared__ float cred[256];
  const int v = blockIdx.y, l = v >> 1;
  const float* avec = ((v & 1) ? aj : ai) + (l << 10);
  const bf16_t* W = gatwb + ((size_t)(l << 10)) * 512;
  const int tid = threadIdx.x, hg = tid >> 6, cc = tid & 63;
  const int c = blockIdx.x * 64 + cc;
  float p = 0.f;
  for (int i = 0; i < 256; ++i) {
    const int h = hg * 256 + i;
    p = fmaf((float)W[(size_t)h * 512 + c], avec[h], p);
  }
  sred[hg][cc] = p;
  float cp = 0.f;
#pragma unroll
  for (int i = 0; i < 4; ++i) cp = fmaf(gWb[(l << 10) + tid + i * 256], avec[tid + i * 256], cp);
  cred[tid] = cp;
  __syncthreads();
  if (tid < 64) wv[v * 512 + blockIdx.x * 64 + tid] = sred[0][tid] + sred[1][tid] + sred[2][tid] + sred[3][tid];
  for (int s = 128; s > 0; s >>= 1) {
    if (tid < s) cred[tid] += cred[tid + s];
    __syncthreads();
  }
  if (tid == 0 && blockIdx.x == 0) con[v] = cred[0] + ((v & 1) ? ajb[l] : aib[l]);
}

// out-attention vectors: wvo[v][c] = sum_d out_W[d][c]*avec[d]; conO[v] = dot(out_Wb, avec).
__global__ __launch_bounds__(256) void k_wvec_o(const float* __restrict__ W, const float* __restrict__ Wb,
                                                const float* __restrict__ ai, const float* __restrict__ aj,
                                                float* __restrict__ wvo, float* __restrict__ conO) {
  const int c = blockIdx.x * 256 + threadIdx.x;     // 0..3071
  const int d0 = blockIdx.y * 64;                   // 8 chunks of 64
  float s1 = 0.f, s2 = 0.f;
  for (int t = 0; t < 64; ++t) {
    const float w = W[(size_t)(d0 + t) * 3072 + c];
    s1 = fmaf(w, ai[d0 + t], s1);
    s2 = fmaf(w, aj[d0 + t], s2);
  }
  atomicAdd(&wvo[c], s1);
  atomicAdd(&wvo[3072 + c], s2);
  if (blockIdx.x == 0 && threadIdx.x < 64) {
    const int d = d0 + threadIdx.x;
    float c1 = Wb[d] * ai[d], c2 = Wb[d] * aj[d];
#pragma unroll
    for (int off = 32; off > 0; off >>= 1) { c1 += __shfl_xor(c1, off); c2 += __shfl_xor(c2, off); }
    if (threadIdx.x == 0) { atomicAdd(&conO[0], c1); atomicAdd(&conO[1], c2); }
  }
}

__global__ __launch_bounds__(256) void k_e12v(const bf16_t* __restrict__ xb,
                                              const float* __restrict__ wv, const float* __restrict__ con,
                                              float* __restrict__ ev) {
  const int tid = threadIdx.x, lane = tid & 63, wid = tid >> 6;
  const int row = blockIdx.x * 4 + wid;
  bf16x8 xv = *(const bf16x8*)(xb + (size_t)row * 512 + lane * 8);
  float xf[8];
#pragma unroll
  for (int j = 0; j < 8; ++j) xf[j] = (float)xv[j];
  float s[6];
#pragma unroll
  for (int v = 0; v < 6; ++v) {
    const float* wp = wv + v * 512 + lane * 8;
    float a = 0.f;
#pragma unroll
    for (int j = 0; j < 8; ++j) a = fmaf(xf[j], wp[j], a);
    s[v] = a;
  }
#pragma unroll
  for (int v = 0; v < 6; ++v)
#pragma unroll
    for (int off = 32; off > 0; off >>= 1) s[v] += __shfl_xor(s[v], off);
  if (lane == 0) {
#pragma unroll
    for (int v = 0; v < 6; ++v) ev[v * 8192 + row] = s[v] + con[v];
  }
}

// fallback: raw row-dots (constants added in k_mask)
__global__ __launch_bounds__(256) void k_eo(const float* __restrict__ Who,
                                            const float* __restrict__ ai, const float* __restrict__ aj,
                                            float* __restrict__ eo1, float* __restrict__ eo2) {
  const int wid = threadIdx.x >> 6, lane = threadIdx.x & 63;
  const int row = blockIdx.x * 4 + wid;
  const float* wr = Who + (size_t)row * 512;
  float s1 = 0.f, s2 = 0.f;
#pragma unroll
  for (int c = 0; c < 2; ++c) {
    const int idx = c * 256 + lane * 4;
    float4 w4 = *(const float4*)&wr[idx];
    float4 a4 = *(const float4*)&ai[idx];
    float4 b4 = *(const float4*)&aj[idx];
    s1 += w4.x * a4.x + w4.y * a4.y + w4.z * a4.z + w4.w * a4.w;
    s2 += w4.x * b4.x + w4.y * b4.y + w4.z * b4.z + w4.w * b4.w;
  }
#pragma unroll
  for (int off = 32; off > 0; off >>= 1) { s1 += __shfl_xor(s1, off); s2 += __shfl_xor(s2, off); }
  if (lane == 0) { eo1[row] = s1; eo2[row] = s2; }
}

// ---------------- block reduce helpers (fallback kernels) ----------------
__device__ __forceinline__ float block_max(float v, float* red) {
#pragma unroll
  for (int off = 32; off > 0; off >>= 1) v = fmaxf(v, __shfl_xor(v, off));
  __syncthreads();
  if ((threadIdx.x & 63) == 0) red[threadIdx.x >> 6] = v;
  __syncthreads();
  return fmaxf(fmaxf(red[0], red[1]), fmaxf(red[2], red[3]));
}
__device__ __forceinline__ float block_sum(float v, float* red) {
#pragma unroll
  for (int off = 32; off > 0; off >>= 1) v += __shfl_xor(v, off);
  __syncthreads();
  if ((threadIdx.x & 63) == 0) red[threadIdx.x >> 6] = v;
  __syncthreads();
  return red[0] + red[1] + red[2] + red[3];
}

// ---------------- GAT attention rows: wave-per-row, all 3 layers, no barriers ----------------
__global__ __launch_bounds__(256) void k_gat_att3(const float* __restrict__ adj, const float* __restrict__ ev,
                                                  bf16_t* __restrict__ att) {
  const int lane = threadIdx.x & 63;
  const int row = blockIdx.x * 4 + (threadIdx.x >> 6);
  const int b = row >> 10;
  const float* arow = adj + (size_t)row * 1024;
  float a[4][4];
#pragma unroll
  for (int c = 0; c < 4; ++c) *(float4*)a[c] = *(const float4*)&arow[(c * 64 + lane) * 4];
#pragma unroll
  for (int l = 0; l < 3; ++l) {
    const float e1v = ev[l * 16384 + row];
    const float* e2r = ev + l * 16384 + 8192 + (b << 10);
    bf16_t* aout = att + (size_t)l * 8388608 + (size_t)row * 1024;
    float s[4][4];
    float mx = -1e30f;
#pragma unroll
    for (int c = 0; c < 4; ++c) {
      float4 e4 = *(const float4*)&e2r[(c * 64 + lane) * 4];
      float ee[4] = {e4.x, e4.y, e4.z, e4.w};
#pragma unroll
      for (int j = 0; j < 4; ++j) {
        float e = e1v + ee[j];
        e = e > 0.f ? e : 0.2f * e;
        s[c][j] = a[c][j] * e;
        mx = fmaxf(mx, s[c][j]);
      }
    }
#pragma unroll
    for (int off = 32; off > 0; off >>= 1) mx = fmaxf(mx, __shfl_xor(mx, off));
    float sum = 0.f;
#pragma unroll
    for (int c = 0; c < 4; ++c)
#pragma unroll
      for (int j = 0; j < 4; ++j) { float p = __expf(s[c][j] - mx); s[c][j] = p; sum += p; }
#pragma unroll
    for (int off = 32; off > 0; off >>= 1) sum += __shfl_xor(sum, off);
    const float inv = 1.f / sum;
#pragma unroll
    for (int c = 0; c < 4; ++c) {
      union { ushort4 u; bf16_t q[4]; } pk;
#pragma unroll
      for (int j = 0; j < 4; ++j) pk.q[j] = (bf16_t)(s[c][j] * inv);
      *(ushort4*)(aout + (c * 64 + lane) * 4) = pk.u;
    }
  }
}

// fallback single-layer version (block-per-row)
__global__ __launch_bounds__(256) void k_gat_att(const float* __restrict__ adj, const float* __restrict__ ev,
                                                 bf16_t* __restrict__ att) {
  __shared__ float red[4];
  const int row = blockIdx.x;
  const int b = row >> 10;
  const float* arow = adj + (size_t)row * 1024;
  const float e1v = ev[row];
  const float* e2r = ev + 8192 + (b << 10);
  float s[4];
  float mx = -1e30f;
#pragma unroll
  for (int c = 0; c < 4; ++c) {
    const int m = c * 256 + threadIdx.x;
    float e = e1v + e2r[m];
    e = e > 0.f ? e : 0.2f * e;
    s[c] = arow[m] * e;
    mx = fmaxf(mx, s[c]);
  }
  mx = block_max(mx, red);
  float sum = 0.f;
#pragma unroll
  for (int c = 0; c < 4; ++c) { float p = __expf(s[c] - mx); s[c] = p; sum += p; }
  sum = block_sum(sum, red);
  const float inv = 1.f / sum;
#pragma unroll
  for (int c = 0; c < 4; ++c) att[(size_t)row * 1024 + c * 256 + threadIdx.x] = (bf16_t)(s[c] * inv);
}

// ---------------- output-attention mask: wave-per-row double softmax ----------------
__global__ __launch_bounds__(256) void k_mask(const float* __restrict__ adj, const float* __restrict__ eo1,
                                              const float* __restrict__ eo2, const float* __restrict__ conO,
                                              const float* __restrict__ aib, const float* __restrict__ ajb,
                                              bf16_t* __restrict__ mask) {
  const int lane = threadIdx.x & 63;
  const int row = blockIdx.x * 4 + (threadIdx.x >> 6);
  const int b = row >> 10;
  const float* arow = adj + (size_t)row * 1024;
  const float t1 = eo1[row] + conO[0] + aib[0];
  const float c2 = conO[1] + ajb[0];
  const float* eor = eo2 + (b << 10);
  float s[4][4];
  float mx = -1e30f;
#pragma unroll
  for (int c = 0; c < 4; ++c) {
    float4 a4 = *(const float4*)&arow[(c * 64 + lane) * 4];
    float4 e4 = *(const float4*)&eor[(c * 64 + lane) * 4];
    float aa[4] = {a4.x, a4.y, a4.z, a4.w};
    float ee[4] = {e4.x, e4.y, e4.z, e4.w};
#pragma unroll
    for (int j = 0; j < 4; ++j) {
      float e = t1 + ee[j] + c2;
      e = e > 0.f ? e : 0.2f * e;
      s[c][j] = aa[j] * e;
      mx = fmaxf(mx, s[c][j]);
    }
  }
#pragma unroll
  for (int off = 32; off > 0; off >>= 1) mx = fmaxf(mx, __shfl_xor(mx, off));
  float sum = 0.f;
#pragma unroll
  for (int c = 0; c < 4; ++c)
#pragma unroll
    for (int j = 0; j < 4; ++j) { float p = __expf(s[c][j] - mx); s[c][j] = p; sum += p; }
#pragma unroll
  for (int off = 32; off > 0; off >>= 1) sum += __shfl_xor(sum, off);
  const float inv = 1.f / sum;        // == max of first softmax
  float sum2 = 0.f;
#pragma unroll
  for (int c = 0; c < 4; ++c)
#pragma unroll
    for (int j = 0; j < 4; ++j) { float p = __expf(s[c][j] * inv - inv); s[c][j] = p; sum2 += p; }
#pragma unroll
  for (int off = 32; off > 0; off >>= 1) sum2 += __shfl_xor(sum2, off);
  const float inv2 = 1.f / sum2;
#pragma unroll
  for (int c = 0; c < 4; ++c) {
    union { ushort4 u; bf16_t q[4]; } pk;
#pragma unroll
    for (int j = 0; j < 4; ++j) pk.q[j] = (bf16_t)(s[c][j] * inv2);
    *(ushort4*)(mask + (size_t)row * 1024 + (c * 64 + lane) * 4) = pk.u;
  }
}

// ---------------- mask transpose ----------------
__global__ __launch_bounds__(256) void k_mtr(const bf16_t* __restrict__ in, bf16_t* __restrict__ out) {
  __shared__ bf16_t T[64][72];
  const int q0 = blockIdx.x * 64, k0 = blockIdx.y * 64, b = blockIdx.z;
  const bf16_t* src = in + ((size_t)b << 20);
  bf16_t* dst = out + ((size_t)b << 20);
  const int r = threadIdx.x >> 2, c = (threadIdx.x & 3) * 16;
  bf16x8 a0 = *(const bf16x8*)(src + (size_t)(q0 + r) * 1024 + k0 + c);
  bf16x8 a1 = *(const bf16x8*)(src + (size_t)(q0 + r) * 1024 + k0 + c + 8);
  *(bf16x8*)&T[r][c] = a0;
  *(bf16x8*)&T[r][c + 8] = a1;
  __syncthreads();
  union { bf16x8 v[2]; bf16_t e[16]; } o;
#pragma unroll
  for (int j = 0; j < 16; ++j) o.e[j] = T[c + j][r];
  *(bf16x8*)(dst + (size_t)(k0 + r) * 1024 + q0 + c) = o.v[0];
  *(bf16x8*)(dst + (size_t)(k0 + r) * 1024 + q0 + c + 8) = o.v[1];
}

// ---------------- MFMA flash attention (XOR-swizzled K/V + P LDS) ----------------
__device__ __forceinline__ int swz(int row, int slot) { return row * 64 + ((slot ^ (row & 7)) << 3); }

__global__ __launch_bounds__(256) void k_flash(const bf16_t* __restrict__ qg, const bf16_t* __restrict__ kg,
                                               const bf16_t* __restrict__ vTg, const bf16_t* __restrict__ maskT,
                                               bf16_t* __restrict__ aout) {
  __shared__ __align__(16) bf16_t Ks[4096];
  __shared__ __align__(16) bf16_t Vs[4096];
  __shared__ __align__(16) bf16_t PL[4][1024];   // per-wave 16x64, swizzled
  const int tid = threadIdx.x, lane = tid & 63, w = tid >> 6;
  const int fr = lane & 15, fq = lane >> 4;
  const int3 bi = xswz3();
  const int n0 = bi.x * 64, hh = bi.y, bb = bi.z;
  const size_t bh = ((size_t)bb * 8 + hh) << 16;
  const bf16_t* q = qg + bh;
  const bf16_t* kk = kg + bh;
  const bf16_t* vT = vTg + bh;
  const bf16_t* mT = maskT + ((size_t)bb << 20);
  bf16_t* PLw = &PL[w][0];

  bf16x8 qf[2];
#pragma unroll
  for (int ks = 0; ks < 2; ++ks)
    qf[ks] = *(const bf16x8*)(q + (size_t)(n0 + w * 16 + fr) * 64 + ks * 32 + fq * 8);

  f32x4 o[4];
#pragma unroll
  for (int nf = 0; nf < 4; ++nf) o[nf] = (f32x4)0.0f;
  float psum[4] = {0.f, 0.f, 0.f, 0.f};

  const int srow = tid >> 2, sslot = (tid & 3) * 2;
  const int ws0 = swz(srow, sslot), ws1 = swz(srow, sslot + 1);
  const int scol = (tid & 3) * 16;

  for (int c = 0; c < 16; ++c) {
    const int k0 = c * 64;
    bf16x8 kv0 = *(const bf16x8*)(kk + (size_t)(k0 + srow) * 64 + scol);
    bf16x8 kv1 = *(const bf16x8*)(kk + (size_t)(k0 + srow) * 64 + scol + 8);
    bf16x8 vv0 = *(const bf16x8*)(vT + (size_t)srow * 1024 + k0 + scol);
    bf16x8 vv1 = *(const bf16x8*)(vT + (size_t)srow * 1024 + k0 + scol + 8);
    union { ushort4 u; bf16_t h[4]; } mfr[4];
#pragma unroll
    for (int nf = 0; nf < 4; ++nf)
      mfr[nf].u = *(const ushort4*)(mT + (size_t)(k0 + nf * 16 + fr) * 1024 + n0 + w * 16 + fq * 4);
    __syncthreads();
    *(bf16x8*)&Ks[ws0] = kv0; *(bf16x8*)&Ks[ws1] = kv1;
    *(bf16x8*)&Vs[ws0] = vv0; *(bf16x8*)&Vs[ws1] = vv1;
    __syncthreads();

    f32x4 s[4];
#pragma unroll
    for (int nf = 0; nf < 4; ++nf) s[nf] = (f32x4)0.0f;
#pragma unroll
    for (int ks = 0; ks < 2; ++ks) {
      bf16x8 kf[4];
#pragma unroll
      for (int nf = 0; nf < 4; ++nf)
        kf[nf] = *(const bf16x8*)&Ks[swz(nf * 16 + fr, ks * 4 + fq)];
#pragma unroll
      for (int nf = 0; nf < 4; ++nf)
        s[nf] = __builtin_amdgcn_mfma_f32_16x16x32_bf16(qf[ks], kf[nf], s[nf], 0, 0, 0);
    }

#pragma unroll
    for (int nf = 0; nf < 4; ++nf)
#pragma unroll
      for (int r = 0; r < 4; ++r) {
        const float p = __expf(s[nf][r] * (float)mfr[nf].h[r]);
        psum[r] += p;
        const int pp = fq * 4 + r, e = nf * 16 + fr;
        PLw[pp * 64 + ((((e >> 3) ^ (pp & 7))) << 3) + (e & 7)] = (bf16_t)p;
      }

#pragma unroll
    for (int ks = 0; ks < 2; ++ks) {
      bf16x8 pf = *(const bf16x8*)&PLw[swz(fr, ks * 4 + fq)];
      bf16x8 vf[4];
#pragma unroll
      for (int nfo = 0; nfo < 4; ++nfo)
        vf[nfo] = *(const bf16x8*)&Vs[swz(nfo * 16 + fr, ks * 4 + fq)];
#pragma unroll
      for (int nfo = 0; nfo < 4; ++nfo)
        o[nfo] = __builtin_amdgcn_mfma_f32_16x16x32_bf16(pf, vf[nfo], o[nfo], 0, 0, 0);
    }
  }

#pragma unroll
  for (int r = 0; r < 4; ++r) {
    psum[r] += __shfl_xor(psum[r], 1);
    psum[r] += __shfl_xor(psum[r], 2);
    psum[r] += __shfl_xor(psum[r], 4);
    psum[r] += __shfl_xor(psum[r], 8);
  }
#pragma unroll
  for (int r = 0; r < 4; ++r) {
    const int tok = n0 + w * 16 + fq * 4 + r;
    const float inv = 1.f / psum[r];
#pragma unroll
    for (int nfo = 0; nfo < 4; ++nfo)
      aout[((size_t)(bb << 10) + tok) * 512 + hh * 64 + nfo * 16 + fr] = (bf16_t)(o[nfo][r] * inv);
  }
}

// ---------------- launcher ----------------
extern "C" void kernel_launch(void* const* d_in, const int* in_sizes, int n_in,
                              void* d_out, int out_size, void* d_ws, size_t ws_size,
                              hipStream_t stream) {
  (void)in_sizes; (void)n_in; (void)out_size;
  const float* x        = (const float*)d_in[0];
  const float* adj      = (const float*)d_in[1];
  const float* qkv_w    = (const float*)d_in[2];
  const float* proj_w   = (const float*)d_in[3];
  const float* proj_b   = (const float*)d_in[4];
  const float* gat_W    = (const float*)d_in[5];
  const float* gat_Wb   = (const float*)d_in[6];
  const float* gat_ai   = (const float*)d_in[7];
  const float* gat_ai_b = (const float*)d_in[8];
  const float* gat_aj   = (const float*)d_in[9];
  const float* gat_aj_b = (const float*)d_in[10];
  const float* out_W    = (const float*)d_in[11];
  const float* out_Wb   = (const float*)d_in[12];
  const float* out_ai   = (const float*)d_in[13];
  const float* out_ai_b = (const float*)d_in[14];
  const float* out_aj   = (const float*)d_in[15];
  const float* out_aj_b = (const float*)d_in[16];

  char* p = (char*)d_ws;
  auto alloc = [&](size_t bytes) { char* r = p; p += (bytes + 255) & ~(size_t)255; return r; };
  bf16_t* xb     = (bf16_t*)alloc(8192ull * 512 * 2);
  bf16_t* qkvwb  = (bf16_t*)alloc(1536ull * 512 * 2);
  bf16_t* gatwb  = (bf16_t*)alloc(3072ull * 512 * 2);
  bf16_t* outwb  = (bf16_t*)alloc(512ull * 3072 * 2);
  bf16_t* projwb = (bf16_t*)alloc(512ull * 512 * 2);
  bf16_t* qb     = (bf16_t*)alloc(8ull * 8 * 1024 * 64 * 2);
  bf16_t* kb     = (bf16_t*)alloc(8ull * 8 * 1024 * 64 * 2);
  bf16_t* vT     = (bf16_t*)alloc(8ull * 8 * 64 * 1024 * 2);
  float*  Who    = (float*)alloc(8192ull * 512 * 4);   // fallback only (dummy hh in big path)
  float*  wv     = (float*)alloc(6 * 512 * 4);
  float*  con    = (float*)alloc(256);
  float*  ev     = (float*)alloc(6 * 8192 * 4);
  float*  eo1    = (float*)alloc(8192 * 4);
  float*  eo2    = (float*)alloc(8192 * 4);
  float*  peo    = (float*)alloc(2ull * 196608 * 4);   // [2][24][8][1024] partials
  // zero-init region: wvo, conO (atomic targets)
  float*  wvo    = (float*)alloc(2 * 3072 * 4);
  float*  conO   = (float*)alloc(256);
  const size_t zspan = (size_t)((char*)conO - (char*)wvo) + 256;

  const bool big = ws_size >= 211000000ull;

  const dim3 blk(256);
  k_cast5<<<8192, blk, 0, stream>>>(x, xb, 1048576, qkv_w, qkvwb, 1245184, gat_W, gatwb, 1638400,
                                    out_W, outwb, 2031616, proj_w, projwb, 2097152);
  hipMemsetAsync(wvo, 0, zspan, stream);
  k_wvec<<<dim3(8, 6), blk, 0, stream>>>(gatwb, gat_Wb, gat_ai, gat_ai_b, gat_aj, gat_aj_b, wv, con);
  k_wvec_o<<<dim3(12, 8), blk, 0, stream>>>(out_W, out_Wb, out_ai, out_aj, wvo, conO);
  k_e12v<<<2048, blk, 0, stream>>>(xb, wv, con, ev);
  k_qkv<<<dim3(12, 64), blk, 0, stream>>>(xb, qkvwb, qb, kb, vT);

  if (big) {
    bf16_t* WhT3 = (bf16_t*)alloc(3ull * 8 * 1024 * 1024 * 2);
    bf16_t* att3 = (bf16_t*)alloc(3ull * 8 * 1024 * 1024 * 2);
    bf16_t* mask  = att3;
    bf16_t* maskT = att3 + 8388608;
    bf16_t* aoutb = att3 + 2 * 8388608;

    k_wh<<<dim3(8, 64, 3), blk, 0, stream>>>(xb, gatwb, gat_Wb, WhT3);
    k_gat_att3<<<2048, blk, 0, stream>>>(adj, ev, att3);
    k_hhat<<<dim3(8, 8, 24), blk, 0, stream>>>(att3, WhT3, (bf16_t*)Who, 3072, wvo, peo);
    k_eored<<<32, blk, 0, stream>>>(peo, eo1, eo2);
    k_mask<<<2048, blk, 0, stream>>>(adj, eo1, eo2, conO, out_ai_b, out_aj_b, mask);
    k_mtr<<<dim3(16, 16, 8), blk, 0, stream>>>(mask, maskT);
    k_flash<<<dim3(16, 8, 8), blk, 0, stream>>>(qb, kb, vT, maskT, aoutb);
    k_lin<<<dim3(4, 64), blk, 0, stream>>>(aoutb, 512, projwb, 512, proj_b, (float*)d_out);
  } else {
    bf16_t* WhT   = (bf16_t*)alloc(8ull * 1024 * 1024 * 2);
    bf16_t* att   = (bf16_t*)alloc(8ull * 1024 * 1024 * 2);
    bf16_t* hh    = (bf16_t*)alloc(8192ull * 1024 * 2);
    bf16_t* aoutb = (bf16_t*)alloc(8192ull * 512 * 2);
    bf16_t* maskT = (bf16_t*)alloc(8ull * 1024 * 1024 * 2);
    bf16_t* mask  = att;

    for (int l = 0; l < 3; ++l) {
      k_wh<<<dim3(8, 64, 1), blk, 0, stream>>>(xb, gatwb + (size_t)l * 524288, gat_Wb + l * 1024, WhT);
      k_gat_att<<<8192, blk, 0, stream>>>(adj, ev + (size_t)l * 16384, att);
      k_hhat<<<dim3(8, 8, 8), blk, 0, stream>>>(att, WhT, hh, 1024, nullptr, nullptr);
      k_who_acc<<<dim3(4, 64), blk, 0, stream>>>(hh, outwb + l * 1024, out_Wb, Who, l);
    }
    k_eo<<<2048, blk, 0, stream>>>(Who, out_ai, out_aj, eo1, eo2);
    k_mask<<<2048, blk, 0, stream>>>(adj, eo1, eo2, conO, out_ai_b, out_aj_b, mask);
    k_mtr<<<dim3(16, 16, 8), blk, 0, stream>>>(mask, maskT);
    k_flash<<<dim3(16, 8, 8), blk, 0, stream>>>(qb, kb, vT, maskT, aoutb);
    k_lin<<<dim3(4, 64), blk, 0, stream>>>(aoutb, 512, projwb, 512, proj_b, (float*)d_out);
  }
}

// Round 13
// 274.409 us; speedup vs baseline: 1.0243x; 1.0243x over previous
//
#include <hip/hip_runtime.h>
#include <math.h>
#include <stdint.h>

#define SCALEQ 0.125f

typedef __bf16 bf16_t;
typedef __bf16 bf16x8 __attribute__((ext_vector_type(8)));
typedef float f32x4 __attribute__((ext_vector_type(4)));

// global -> LDS async copy, 16B per lane. LDS dest is wave-uniform base + lane*16.
#define GLOAD_LDS16(gsrc, ldst)                                                   \
  __builtin_amdgcn_global_load_lds(                                               \
      (const __attribute__((address_space(1))) void*)(uintptr_t)(const void*)(gsrc), \
      (__attribute__((address_space(3))) void*)(uintptr_t)(void*)(ldst), 16, 0, 0)

// XCD-chunked bijective block swizzle (grid total must be %8==0).
__device__ __forceinline__ int3 xswz3() {
  const int nx = gridDim.x, ny = gridDim.y;
  int lin = (blockIdx.z * ny + blockIdx.y) * nx + blockIdx.x;
  const int n = nx * ny * gridDim.z;
  int work = (lin & 7) * (n >> 3) + (lin >> 3);
  int3 r;
  r.x = work % nx; work /= nx;
  r.y = work % ny; r.z = work / ny;
  return r;
}

// ---------------- bf16 MFMA GEMM core (128x128 tile, 4 waves, BK=64) ----------------
// Rule-#21 XOR swizzle: linear LDS dest, per-lane global SOURCE chunk permuted,
// reads apply the same involution (verified: SQ_LDS_BANK_CONFLICT == 0).
__device__ __forceinline__ void mm_bf16(const bf16_t* __restrict__ A, int lda,
                                        const bf16_t* __restrict__ B, int ldb,
                                        int K, int m0, int n0,
                                        bf16_t* As, bf16_t* Bs, f32x4 (&acc)[4][4]) {
  const int tid = threadIdx.x, lane = tid & 63, w = tid >> 6;
  const int wr = (w >> 1) * 64, wc = (w & 1) * 64;
  const int fr = lane & 15, fq = lane >> 4;
  const int c8 = (((lane & 7) ^ ((lane >> 3) & 7)) * 8);   // swizzled source chunk
  for (int kt = 0; kt < K; kt += 64) {
    __syncthreads();
#pragma unroll
    for (int t = 0; t < 4; ++t) {
      const int rl = t * 32 + w * 8 + (lane >> 3);
      GLOAD_LDS16(A + (size_t)(m0 + rl) * lda + kt + c8, As + (t * 32 + w * 8) * 64);
      GLOAD_LDS16(B + (size_t)(n0 + rl) * ldb + kt + c8, Bs + (t * 32 + w * 8) * 64);
    }
    __syncthreads();
#pragma unroll
    for (int ks = 0; ks < 2; ++ks) {
      bf16x8 af[4], bfv[4];
      const int ch = (((ks * 4 + fq) ^ (fr & 7)) << 3);
#pragma unroll
      for (int mf = 0; mf < 4; ++mf)
        af[mf] = *(const bf16x8*)(As + (wr + mf * 16 + fr) * 64 + ch);
#pragma unroll
      for (int nf = 0; nf < 4; ++nf)
        bfv[nf] = *(const bf16x8*)(Bs + (wc + nf * 16 + fr) * 64 + ch);
#pragma unroll
      for (int mf = 0; mf < 4; ++mf)
#pragma unroll
        for (int nf = 0; nf < 4; ++nf)
          acc[mf][nf] = __builtin_amdgcn_mfma_f32_16x16x32_bf16(af[mf], bfv[nf], acc[mf][nf], 0, 0, 0);
    }
  }
}

#define MM_PROLOGUE()                                  \
  __shared__ __align__(16) bf16_t As[128 * 64];        \
  __shared__ __align__(16) bf16_t Bs[128 * 64];        \
  f32x4 acc[4][4];                                     \
  _Pragma("unroll") for (int i_ = 0; i_ < 4; ++i_)     \
  _Pragma("unroll") for (int j_ = 0; j_ < 4; ++j_) acc[i_][j_] = (f32x4)0.0f;

#define MM_EPI_SETUP(M0, N0)                                   \
  const int lane = threadIdx.x & 63, w = threadIdx.x >> 6;     \
  const int fr = lane & 15, fq = lane >> 4;                    \
  const int mb = (M0) + (w >> 1) * 64, nb = (N0) + (w & 1) * 64;

// ---------------- GEMM kernels ----------------
__global__ __launch_bounds__(256) void k_qkv(const bf16_t* __restrict__ xb, const bf16_t* __restrict__ wb,
                                             bf16_t* __restrict__ qb, bf16_t* __restrict__ kb,
                                             bf16_t* __restrict__ vT) {
  MM_PROLOGUE();
  const int3 bi = xswz3();
  const int m0 = bi.y * 128, n0 = bi.x * 128;
  mm_bf16(xb, 512, wb, 512, 512, m0, n0, As, Bs, acc);
  MM_EPI_SETUP(m0, n0);
#pragma unroll
  for (int mf = 0; mf < 4; ++mf)
#pragma unroll
    for (int nf = 0; nf < 4; ++nf) {
      const int n = nb + nf * 16 + fr;
      const int which = n >> 9, hd = (n >> 6) & 7, d = n & 63;
      const int m_ = mb + mf * 16 + fq * 4;
      const int b = m_ >> 10, tok0 = m_ & 1023;
      if (which == 2) {
        union { ushort4 u; bf16_t q[4]; } pk;
#pragma unroll
        for (int r = 0; r < 4; ++r) pk.q[r] = (bf16_t)acc[mf][nf][r];
        *(ushort4*)(vT + (((size_t)b * 8 + hd) * 64 + d) * 1024 + tok0) = pk.u;
      } else {
        bf16_t* dst = which ? kb : qb;
        const float sc = which ? 1.f : SCALEQ;
#pragma unroll
        for (int r = 0; r < 4; ++r)
          dst[(((size_t)b * 8 + hd) * 1024 + tok0 + r) * 64 + d] = (bf16_t)(acc[mf][nf][r] * sc);
      }
    }
}

__global__ __launch_bounds__(256) void k_wh(const bf16_t* __restrict__ xb, const bf16_t* __restrict__ gatw,
                                            const float* __restrict__ gWb, bf16_t* __restrict__ WhT) {
  MM_PROLOGUE();
  const int3 bi = xswz3();
  const int m0 = bi.y * 128, n0 = bi.x * 128, l = bi.z;
  const bf16_t* Wl = gatw + (size_t)l * 524288;
  const float* Wb = gWb + l * 1024;
  bf16_t* out = WhT + (size_t)l * 8388608;
  mm_bf16(xb, 512, Wl, 512, 512, m0, n0, As, Bs, acc);
  MM_EPI_SETUP(m0, n0);
#pragma unroll
  for (int mf = 0; mf < 4; ++mf)
#pragma unroll
    for (int nf = 0; nf < 4; ++nf) {
      const int h = nb + nf * 16 + fr;
      const float bias = Wb[h];
      const int m_ = mb + mf * 16 + fq * 4;
      const int b = m_ >> 10, ml = m_ & 1023;
      union { ushort4 u; bf16_t q[4]; } pk;
#pragma unroll
      for (int r = 0; r < 4; ++r) pk.q[r] = (bf16_t)(acc[mf][nf][r] + bias);
      *(ushort4*)(out + (((size_t)b << 10) + h) * 1024 + ml) = pk.u;
    }
}

// ---- 256^2-tile, 8-wave, double-buffered 2-phase (issue-early) hhat ----
// grid (4,4,24): per problem C[1024x1024] in 256^2 tiles. Fused eo-dot epilogue:
// peo[2][24][16][1024] per-(blockx,wavecol) partials (each slot written once).
__global__ __launch_bounds__(512) void k_hhat256(const bf16_t* __restrict__ att, const bf16_t* __restrict__ WhT,
                                                 const float* __restrict__ wvo, float* __restrict__ peo) {
  __shared__ __align__(16) bf16_t LA[2][256 * 64];
  __shared__ __align__(16) bf16_t LB[2][256 * 64];
  const int tid = threadIdx.x, lane = tid & 63, w = tid >> 6;   // w 0..7
  const int fr = lane & 15, fq = lane >> 4;
  const int3 bi = xswz3();
  const int prob = bi.z, l = prob >> 3;
  const size_t off = ((size_t)prob) << 20;
  const bf16_t* A = att + off;
  const bf16_t* B = WhT + off;
  const int m0 = bi.y * 256, n0 = bi.x * 256;
  const int srow = w * 32 + (lane >> 3);                        // + t*8
  const int c8 = (((lane & 7) ^ ((lane >> 3) & 7)) * 8);        // swizzled source chunk

  f32x4 acc[8][4];
#pragma unroll
  for (int mf = 0; mf < 8; ++mf)
#pragma unroll
    for (int nf = 0; nf < 4; ++nf) acc[mf][nf] = (f32x4)0.0f;

  // prologue: stage tile 0 into buf 0
  {
    const int kofs = c8;
#pragma unroll
    for (int t = 0; t < 4; ++t) {
      const int r = srow + t * 8;
      GLOAD_LDS16(A + (size_t)(m0 + r) * 1024 + kofs, &LA[0][(w * 32 + t * 8) * 64]);
      GLOAD_LDS16(B + (size_t)(n0 + r) * 1024 + kofs, &LB[0][(w * 32 + t * 8) * 64]);
    }
  }
  __syncthreads();   // drains vmcnt(0): buf0 ready

  const int wrow = (w >> 2) * 128, wcol = (w & 3) * 64;
  for (int t = 0; t < 16; ++t) {
    const int cur = t & 1;
    if (t < 15) {      // issue next tile early; lands under this tile's MFMAs
      const int kofs = (t + 1) * 64 + c8;
#pragma unroll
      for (int u = 0; u < 4; ++u) {
        const int r = srow + u * 8;
        GLOAD_LDS16(A + (size_t)(m0 + r) * 1024 + kofs, &LA[cur ^ 1][(w * 32 + u * 8) * 64]);
        GLOAD_LDS16(B + (size_t)(n0 + r) * 1024 + kofs, &LB[cur ^ 1][(w * 32 + u * 8) * 64]);
      }
    }
    const bf16_t* la = &LA[cur][0];
    const bf16_t* lb = &LB[cur][0];
#pragma unroll
    for (int ks = 0; ks < 2; ++ks) {
      const int ch = (((ks * 4 + fq) ^ (fr & 7)) << 3);
      bf16x8 bfv[4];
#pragma unroll
      for (int nf = 0; nf < 4; ++nf)
        bfv[nf] = *(const bf16x8*)(lb + (wcol + nf * 16 + fr) * 64 + ch);
#pragma unroll
      for (int mf = 0; mf < 8; ++mf) {
        bf16x8 af = *(const bf16x8*)(la + (wrow + mf * 16 + fr) * 64 + ch);
#pragma unroll
        for (int nf = 0; nf < 4; ++nf)
          acc[mf][nf] = __builtin_amdgcn_mfma_f32_16x16x32_bf16(af, bfv[nf], acc[mf][nf], 0, 0, 0);
      }
    }
    __syncthreads();   // everyone done reading buf[cur]; next tile's loads drained
  }

  // fused eo-dot epilogue (f32 pre-rounding elu values)
  float w1[4], w2[4];
#pragma unroll
  for (int nf = 0; nf < 4; ++nf) {
    const int n = n0 + wcol + nf * 16 + fr;
    w1[nf] = wvo[l * 1024 + n];
    w2[nf] = wvo[3072 + l * 1024 + n];
  }
  float* p1 = peo + (((size_t)prob * 16) + bi.x * 4 + (w & 3)) * 1024;
  float* p2 = p1 + 393216;   // 24*16*1024
#pragma unroll
  for (int mf = 0; mf < 8; ++mf)
#pragma unroll
    for (int r = 0; r < 4; ++r) {
      float s1 = 0.f, s2 = 0.f;
#pragma unroll
      for (int nf = 0; nf < 4; ++nf) {
        float v = acc[mf][nf][r];
        v = v > 0.f ? v : (__expf(v) - 1.f);
        s1 = fmaf(v, w1[nf], s1);
        s2 = fmaf(v, w2[nf], s2);
      }
      s1 += __shfl_xor(s1, 1); s1 += __shfl_xor(s1, 2); s1 += __shfl_xor(s1, 4); s1 += __shfl_xor(s1, 8);
      s2 += __shfl_xor(s2, 1); s2 += __shfl_xor(s2, 2); s2 += __shfl_xor(s2, 4); s2 += __shfl_xor(s2, 8);
      if (fr == 0) {
        const int rowloc = m0 + wrow + mf * 16 + fq * 4 + r;   // 0..1023
        p1[rowloc] = s1;
        p2[rowloc] = s2;
      }
    }
}

// fallback-path hhat (128^2): writes hh
__global__ __launch_bounds__(256) void k_hhat(const bf16_t* __restrict__ att, const bf16_t* __restrict__ WhT,
                                              bf16_t* __restrict__ hh, int ldh) {
  MM_PROLOGUE();
  const int3 bi = xswz3();
  const int m0 = bi.y * 128, n0 = bi.x * 128;
  const int prob = bi.z;
  const int l = prob >> 3, bz = prob & 7;
  const size_t off = ((size_t)prob) << 20;
  mm_bf16(att + off, 1024, WhT + off, 1024, 1024, m0, n0, As, Bs, acc);
  MM_EPI_SETUP(m0, n0);
#pragma unroll
  for (int mf = 0; mf < 4; ++mf)
#pragma unroll
    for (int nf = 0; nf < 4; ++nf) {
      const int n = nb + nf * 16 + fr;
#pragma unroll
      for (int r = 0; r < 4; ++r) {
        const int m = mb + mf * 16 + fq * 4 + r;
        float v = acc[mf][nf][r];
        v = v > 0.f ? v : (__expf(v) - 1.f);
        hh[(size_t)((bz << 10) + m) * ldh + l * 1024 + n] = (bf16_t)v;
      }
    }
}

// reduce peo partials -> eo1/eo2 (raw sums; constants added in k_mask)
__global__ __launch_bounds__(256) void k_eored(const float* __restrict__ peo,
                                               float* __restrict__ eo1, float* __restrict__ eo2) {
  const int m = blockIdx.x * 256 + threadIdx.x;   // 0..8191
  const int b = m >> 10, r = m & 1023;
  float s1 = 0.f, s2 = 0.f;
#pragma unroll
  for (int l = 0; l < 3; ++l)
#pragma unroll
    for (int s = 0; s < 16; ++s) {
      const size_t idx = (((size_t)(l * 8 + b)) * 16 + s) * 1024 + r;
      s1 += peo[idx];
      s2 += peo[393216 + idx];
    }
  eo1[m] = s1;
  eo2[m] = s2;
}

__global__ __launch_bounds__(256) void k_lin(const bf16_t* __restrict__ A, int lda,
                                             const bf16_t* __restrict__ B, int K,
                                             const float* __restrict__ bias, float* __restrict__ out) {
  MM_PROLOGUE();
  const int3 bi = xswz3();
  const int m0 = bi.y * 128, n0 = bi.x * 128;
  mm_bf16(A, lda, B, K, K, m0, n0, As, Bs, acc);
  MM_EPI_SETUP(m0, n0);
#pragma unroll
  for (int mf = 0; mf < 4; ++mf)
#pragma unroll
    for (int nf = 0; nf < 4; ++nf) {
      const int n = nb + nf * 16 + fr;
#pragma unroll
      for (int r = 0; r < 4; ++r) {
        const int m = mb + mf * 16 + fq * 4 + r;
        out[(size_t)m * 512 + n] = acc[mf][nf][r] + bias[n];
      }
    }
}

// fallback: Who (+)= hh @ out_W[:, l*1024:+1024].T (bias folded at l==0)
__global__ __launch_bounds__(256) void k_who_acc(const bf16_t* __restrict__ hh, const bf16_t* __restrict__ Wl,
                                                 const float* __restrict__ Wb, float* __restrict__ Who, int l) {
  MM_PROLOGUE();
  const int m0 = blockIdx.y * 128, n0 = blockIdx.x * 128;
  mm_bf16(hh, 1024, Wl, 3072, 1024, m0, n0, As, Bs, acc);
  MM_EPI_SETUP(m0, n0);
#pragma unroll
  for (int mf = 0; mf < 4; ++mf)
#pragma unroll
    for (int nf = 0; nf < 4; ++nf) {
      const int n = nb + nf * 16 + fr;
#pragma unroll
      for (int r = 0; r < 4; ++r) {
        const int m = mb + mf * 16 + fq * 4 + r;
        const size_t idx = (size_t)m * 512 + n;
        Who[idx] = acc[mf][nf][r] + (l == 0 ? Wb[n] : Who[idx]);
      }
    }
}

// ---------------- fused casts f32 -> bf16 (5 segments) ----------------
__global__ __launch_bounds__(256) void k_cast5(const float* __restrict__ s0, bf16_t* __restrict__ d0, int c0,
                                               const float* __restrict__ s1, bf16_t* __restrict__ d1, int c1,
                                               const float* __restrict__ s2, bf16_t* __restrict__ d2, int c2,
                                               const float* __restrict__ s3, bf16_t* __restrict__ d3, int c3,
                                               const float* __restrict__ s4, bf16_t* __restrict__ d4, int c4) {
  int i = blockIdx.x * 256 + threadIdx.x;
  const float* src; bf16_t* dst; int j;
  if (i < c0)      { src = s0; dst = d0; j = i; }
  else if (i < c1) { src = s1; dst = d1; j = i - c0; }
  else if (i < c2) { src = s2; dst = d2; j = i - c1; }
  else if (i < c3) { src = s3; dst = d3; j = i - c2; }
  else if (i < c4) { src = s4; dst = d4; j = i - c3; }
  else return;
  float4 v = ((const float4*)src)[j];
  union { ushort4 u; bf16_t b[4]; } p;
  p.b[0] = (bf16_t)v.x; p.b[1] = (bf16_t)v.y; p.b[2] = (bf16_t)v.z; p.b[3] = (bf16_t)v.w;
  ((ushort4*)dst)[j] = p.u;
}

// ---------------- algebraic e1/e2 (gat layers) ----------------
__global__ __launch_bounds__(256) void k_wvec(const bf16_t* __restrict__ gatwb,
                                              const float* __restrict__ gWb,
                                              const float* __restrict__ ai, const float* __restrict__ aib,
                                              const float* __restrict__ aj, const float* __restrict__ ajb,
                                              float* __restrict__ wv, float* __restrict__ con) {
  __shared__ float sred[4][64];
  __shared__ float cred[256];
  const int v = blockIdx.y, l = v >> 1;
  const float* avec = ((v & 1) ? aj : ai) + (l << 10);
  const bf16_t* W = gatwb + ((size_t)(l << 10)) * 512;
  const int tid = threadIdx.x, hg = tid >> 6, cc = tid & 63;
  const int c = blockIdx.x * 64 + cc;
  float p = 0.f;
  for (int i = 0; i < 256; ++i) {
    const int h = hg * 256 + i;
    p = fmaf((float)W[(size_t)h * 512 + c], avec[h], p);
  }
  sred[hg][cc] = p;
  float cp = 0.f;
#pragma unroll
  for (int i = 0; i < 4; ++i) cp = fmaf(gWb[(l << 10) + tid + i * 256], avec[tid + i * 256], cp);
  cred[tid] = cp;
  __syncthreads();
  if (tid < 64) wv[v * 512 + blockIdx.x * 64 + tid] = sred[0][tid] + sred[1][tid] + sred[2][tid] + sred[3][tid];
  for (int s = 128; s > 0; s >>= 1) {
    if (tid < s) cred[tid] += cred[tid + s];
    __syncthreads();
  }
  if (tid == 0 && blockIdx.x == 0) con[v] = cred[0] + ((v & 1) ? ajb[l] : aib[l]);
}

// out-attention vectors: wvo[v][c] = sum_d out_W[d][c]*avec[d]; conO[v] = dot(out_Wb, avec).
__global__ __launch_bounds__(256) void k_wvec_o(const float* __restrict__ W, const float* __restrict__ Wb,
                                                const float* __restrict__ ai, const float* __restrict__ aj,
                                                float* __restrict__ wvo, float* __restrict__ conO) {
  const int c = blockIdx.x * 256 + threadIdx.x;     // 0..3071
  const int d0 = blockIdx.y * 64;                   // 8 chunks of 64
  float s1 = 0.f, s2 = 0.f;
  for (int t = 0; t < 64; ++t) {
    const float w = W[(size_t)(d0 + t) * 3072 + c];
    s1 = fmaf(w, ai[d0 + t], s1);
    s2 = fmaf(w, aj[d0 + t], s2);
  }
  atomicAdd(&wvo[c], s1);
  atomicAdd(&wvo[3072 + c], s2);
  if (blockIdx.x == 0 && threadIdx.x < 64) {
    const int d = d0 + threadIdx.x;
    float c1 = Wb[d] * ai[d], c2 = Wb[d] * aj[d];
#pragma unroll
    for (int off = 32; off > 0; off >>= 1) { c1 += __shfl_xor(c1, off); c2 += __shfl_xor(c2, off); }
    if (threadIdx.x == 0) { atomicAdd(&conO[0], c1); atomicAdd(&conO[1], c2); }
  }
}

__global__ __launch_bounds__(256) void k_e12v(const bf16_t* __restrict__ xb,
                                              const float* __restrict__ wv, const float* __restrict__ con,
                                              float* __restrict__ ev) {
  const int tid = threadIdx.x, lane = tid & 63, wid = tid >> 6;
  const int row = blockIdx.x * 4 + wid;
  bf16x8 xv = *(const bf16x8*)(xb + (size_t)row * 512 + lane * 8);
  float xf[8];
#pragma unroll
  for (int j = 0; j < 8; ++j) xf[j] = (float)xv[j];
  float s[6];
#pragma unroll
  for (int v = 0; v < 6; ++v) {
    const float* wp = wv + v * 512 + lane * 8;
    float a = 0.f;
#pragma unroll
    for (int j = 0; j < 8; ++j) a = fmaf(xf[j], wp[j], a);
    s[v] = a;
  }
#pragma unroll
  for (int v = 0; v < 6; ++v)
#pragma unroll
    for (int off = 32; off > 0; off >>= 1) s[v] += __shfl_xor(s[v], off);
  if (lane == 0) {
#pragma unroll
    for (int v = 0; v < 6; ++v) ev[v * 8192 + row] = s[v] + con[v];
  }
}

// fallback: raw row-dots (constants added in k_mask)
__global__ __launch_bounds__(256) void k_eo(const float* __restrict__ Who,
                                            const float* __restrict__ ai, const float* __restrict__ aj,
                                            float* __restrict__ eo1, float* __restrict__ eo2) {
  const int wid = threadIdx.x >> 6, lane = threadIdx.x & 63;
  const int row = blockIdx.x * 4 + wid;
  const float* wr = Who + (size_t)row * 512;
  float s1 = 0.f, s2 = 0.f;
#pragma unroll
  for (int c = 0; c < 2; ++c) {
    const int idx = c * 256 + lane * 4;
    float4 w4 = *(const float4*)&wr[idx];
    float4 a4 = *(const float4*)&ai[idx];
    float4 b4 = *(const float4*)&aj[idx];
    s1 += w4.x * a4.x + w4.y * a4.y + w4.z * a4.z + w4.w * a4.w;
    s2 += w4.x * b4.x + w4.y * b4.y + w4.z * b4.z + w4.w * b4.w;
  }
#pragma unroll
  for (int off = 32; off > 0; off >>= 1) { s1 += __shfl_xor(s1, off); s2 += __shfl_xor(s2, off); }
  if (lane == 0) { eo1[row] = s1; eo2[row] = s2; }
}

// ---------------- block reduce helpers (fallback kernels) ----------------
__device__ __forceinline__ float block_max(float v, float* red) {
#pragma unroll
  for (int off = 32; off > 0; off >>= 1) v = fmaxf(v, __shfl_xor(v, off));
  __syncthreads();
  if ((threadIdx.x & 63) == 0) red[threadIdx.x >> 6] = v;
  __syncthreads();
  return fmaxf(fmaxf(red[0], red[1]), fmaxf(red[2], red[3]));
}
__device__ __forceinline__ float block_sum(float v, float* red) {
#pragma unroll
  for (int off = 32; off > 0; off >>= 1) v += __shfl_xor(v, off);
  __syncthreads();
  if ((threadIdx.x & 63) == 0) red[threadIdx.x >> 6] = v;
  __syncthreads();
  return red[0] + red[1] + red[2] + red[3];
}

// ---------------- GAT attention rows: wave-per-row, all 3 layers, no barriers ----------------
__global__ __launch_bounds__(256) void k_gat_att3(const float* __restrict__ adj, const float* __restrict__ ev,
                                                  bf16_t* __restrict__ att) {
  const int lane = threadIdx.x & 63;
  const int row = blockIdx.x * 4 + (threadIdx.x >> 6);
  const int b = row >> 10;
  const float* arow = adj + (size_t)row * 1024;
  float a[4][4];
#pragma unroll
  for (int c = 0; c < 4; ++c) *(float4*)a[c] = *(const float4*)&arow[(c * 64 + lane) * 4];
#pragma unroll
  for (int l = 0; l < 3; ++l) {
    const float e1v = ev[l * 16384 + row];
    const float* e2r = ev + l * 16384 + 8192 + (b << 10);
    bf16_t* aout = att + (size_t)l * 8388608 + (size_t)row * 1024;
    float s[4][4];
    float mx = -1e30f;
#pragma unroll
    for (int c = 0; c < 4; ++c) {
      float4 e4 = *(const float4*)&e2r[(c * 64 + lane) * 4];
      float ee[4] = {e4.x, e4.y, e4.z, e4.w};
#pragma unroll
      for (int j = 0; j < 4; ++j) {
        float e = e1v + ee[j];
        e = e > 0.f ? e : 0.2f * e;
        s[c][j] = a[c][j] * e;
        mx = fmaxf(mx, s[c][j]);
      }
    }
#pragma unroll
    for (int off = 32; off > 0; off >>= 1) mx = fmaxf(mx, __shfl_xor(mx, off));
    float sum = 0.f;
#pragma unroll
    for (int c = 0; c < 4; ++c)
#pragma unroll
      for (int j = 0; j < 4; ++j) { float p = __expf(s[c][j] - mx); s[c][j] = p; sum += p; }
#pragma unroll
    for (int off = 32; off > 0; off >>= 1) sum += __shfl_xor(sum, off);
    const float inv = 1.f / sum;
#pragma unroll
    for (int c = 0; c < 4; ++c) {
      union { ushort4 u; bf16_t q[4]; } pk;
#pragma unroll
      for (int j = 0; j < 4; ++j) pk.q[j] = (bf16_t)(s[c][j] * inv);
      *(ushort4*)(aout + (c * 64 + lane) * 4) = pk.u;
    }
  }
}

// fallback single-layer version (block-per-row)
__global__ __launch_bounds__(256) void k_gat_att(const float* __restrict__ adj, const float* __restrict__ ev,
                                                 bf16_t* __restrict__ att) {
  __shared__ float red[4];
  const int row = blockIdx.x;
  const int b = row >> 10;
  const float* arow = adj + (size_t)row * 1024;
  const float e1v = ev[row];
  const float* e2r = ev + 8192 + (b << 10);
  float s[4];
  float mx = -1e30f;
#pragma unroll
  for (int c = 0; c < 4; ++c) {
    const int m = c * 256 + threadIdx.x;
    float e = e1v + e2r[m];
    e = e > 0.f ? e : 0.2f * e;
    s[c] = arow[m] * e;
    mx = fmaxf(mx, s[c]);
  }
  mx = block_max(mx, red);
  float sum = 0.f;
#pragma unroll
  for (int c = 0; c < 4; ++c) { float p = __expf(s[c] - mx); s[c] = p; sum += p; }
  sum = block_sum(sum, red);
  const float inv = 1.f / sum;
#pragma unroll
  for (int c = 0; c < 4; ++c) att[(size_t)row * 1024 + c * 256 + threadIdx.x] = (bf16_t)(s[c] * inv);
}

// ---------------- output-attention mask: wave-per-row double softmax ----------------
__global__ __launch_bounds__(256) void k_mask(const float* __restrict__ adj, const float* __restrict__ eo1,
                                              const float* __restrict__ eo2, const float* __restrict__ conO,
                                              const float* __restrict__ aib, const float* __restrict__ ajb,
                                              bf16_t* __restrict__ mask) {
  const int lane = threadIdx.x & 63;
  const int row = blockIdx.x * 4 + (threadIdx.x >> 6);
  const int b = row >> 10;
  const float* arow = adj + (size_t)row * 1024;
  const float t1 = eo1[row] + conO[0] + aib[0];
  const float c2 = conO[1] + ajb[0];
  const float* eor = eo2 + (b << 10);
  float s[4][4];
  float mx = -1e30f;
#pragma unroll
  for (int c = 0; c < 4; ++c) {
    float4 a4 = *(const float4*)&arow[(c * 64 + lane) * 4];
    float4 e4 = *(const float4*)&eor[(c * 64 + lane) * 4];
    float aa[4] = {a4.x, a4.y, a4.z, a4.w};
    float ee[4] = {e4.x, e4.y, e4.z, e4.w};
#pragma unroll
    for (int j = 0; j < 4; ++j) {
      float e = t1 + ee[j] + c2;
      e = e > 0.f ? e : 0.2f * e;
      s[c][j] = aa[j] * e;
      mx = fmaxf(mx, s[c][j]);
    }
  }
#pragma unroll
  for (int off = 32; off > 0; off >>= 1) mx = fmaxf(mx, __shfl_xor(mx, off));
  float sum = 0.f;
#pragma unroll
  for (int c = 0; c < 4; ++c)
#pragma unroll
    for (int j = 0; j < 4; ++j) { float p = __expf(s[c][j] - mx); s[c][j] = p; sum += p; }
#pragma unroll
  for (int off = 32; off > 0; off >>= 1) sum += __shfl_xor(sum, off);
  const float inv = 1.f / sum;        // == max of first softmax
  float sum2 = 0.f;
#pragma unroll
  for (int c = 0; c < 4; ++c)
#pragma unroll
    for (int j = 0; j < 4; ++j) { float p = __expf(s[c][j] * inv - inv); s[c][j] = p; sum2 += p; }
#pragma unroll
  for (int off = 32; off > 0; off >>= 1) sum2 += __shfl_xor(sum2, off);
  const float inv2 = 1.f / sum2;
#pragma unroll
  for (int c = 0; c < 4; ++c) {
    union { ushort4 u; bf16_t q[4]; } pk;
#pragma unroll
    for (int j = 0; j < 4; ++j) pk.q[j] = (bf16_t)(s[c][j] * inv2);
    *(ushort4*)(mask + (size_t)row * 1024 + (c * 64 + lane) * 4) = pk.u;
  }
}

// ---------------- mask transpose ----------------
__global__ __launch_bounds__(256) void k_mtr(const bf16_t* __restrict__ in, bf16_t* __restrict__ out) {
  __shared__ bf16_t T[64][72];
  const int q0 = blockIdx.x * 64, k0 = blockIdx.y * 64, b = blockIdx.z;
  const bf16_t* src = in + ((size_t)b << 20);
  bf16_t* dst = out + ((size_t)b << 20);
  const int r = threadIdx.x >> 2, c = (threadIdx.x & 3) * 16;
  bf16x8 a0 = *(const bf16x8*)(src + (size_t)(q0 + r) * 1024 + k0 + c);
  bf16x8 a1 = *(const bf16x8*)(src + (size_t)(q0 + r) * 1024 + k0 + c + 8);
  *(bf16x8*)&T[r][c] = a0;
  *(bf16x8*)&T[r][c + 8] = a1;
  __syncthreads();
  union { bf16x8 v[2]; bf16_t e[16]; } o;
#pragma unroll
  for (int j = 0; j < 16; ++j) o.e[j] = T[c + j][r];
  *(bf16x8*)(dst + (size_t)(k0 + r) * 1024 + q0 + c) = o.v[0];
  *(bf16x8*)(dst + (size_t)(k0 + r) * 1024 + q0 + c + 8) = o.v[1];
}

// ---------------- MFMA flash attention (XOR-swizzled K/V + P LDS) ----------------
__device__ __forceinline__ int swz(int row, int slot) { return row * 64 + ((slot ^ (row & 7)) << 3); }

__global__ __launch_bounds__(256) void k_flash(const bf16_t* __restrict__ qg, const bf16_t* __restrict__ kg,
                                               const bf16_t* __restrict__ vTg, const bf16_t* __restrict__ maskT,
                                               bf16_t* __restrict__ aout) {
  __shared__ __align__(16) bf16_t Ks[4096];
  __shared__ __align__(16) bf16_t Vs[4096];
  __shared__ __align__(16) bf16_t PL[4][1024];   // per-wave 16x64, swizzled
  const int tid = threadIdx.x, lane = tid & 63, w = tid >> 6;
  const int fr = lane & 15, fq = lane >> 4;
  const int3 bi = xswz3();
  const int n0 = bi.x * 64, hh = bi.y, bb = bi.z;
  const size_t bh = ((size_t)bb * 8 + hh) << 16;
  const bf16_t* q = qg + bh;
  const bf16_t* kk = kg + bh;
  const bf16_t* vT = vTg + bh;
  const bf16_t* mT = maskT + ((size_t)bb << 20);
  bf16_t* PLw = &PL[w][0];

  bf16x8 qf[2];
#pragma unroll
  for (int ks = 0; ks < 2; ++ks)
    qf[ks] = *(const bf16x8*)(q + (size_t)(n0 + w * 16 + fr) * 64 + ks * 32 + fq * 8);

  f32x4 o[4];
#pragma unroll
  for (int nf = 0; nf < 4; ++nf) o[nf] = (f32x4)0.0f;
  float psum[4] = {0.f, 0.f, 0.f, 0.f};

  const int srow = tid >> 2, sslot = (tid & 3) * 2;
  const int ws0 = swz(srow, sslot), ws1 = swz(srow, sslot + 1);
  const int scol = (tid & 3) * 16;

  for (int c = 0; c < 16; ++c) {
    const int k0 = c * 64;
    bf16x8 kv0 = *(const bf16x8*)(kk + (size_t)(k0 + srow) * 64 + scol);
    bf16x8 kv1 = *(const bf16x8*)(kk + (size_t)(k0 + srow) * 64 + scol + 8);
    bf16x8 vv0 = *(const bf16x8*)(vT + (size_t)srow * 1024 + k0 + scol);
    bf16x8 vv1 = *(const bf16x8*)(vT + (size_t)srow * 1024 + k0 + scol + 8);
    union { ushort4 u; bf16_t h[4]; } mfr[4];
#pragma unroll
    for (int nf = 0; nf < 4; ++nf)
      mfr[nf].u = *(const ushort4*)(mT + (size_t)(k0 + nf * 16 + fr) * 1024 + n0 + w * 16 + fq * 4);
    __syncthreads();
    *(bf16x8*)&Ks[ws0] = kv0; *(bf16x8*)&Ks[ws1] = kv1;
    *(bf16x8*)&Vs[ws0] = vv0; *(bf16x8*)&Vs[ws1] = vv1;
    __syncthreads();

    f32x4 s[4];
#pragma unroll
    for (int nf = 0; nf < 4; ++nf) s[nf] = (f32x4)0.0f;
#pragma unroll
    for (int ks = 0; ks < 2; ++ks) {
      bf16x8 kf[4];
#pragma unroll
      for (int nf = 0; nf < 4; ++nf)
        kf[nf] = *(const bf16x8*)&Ks[swz(nf * 16 + fr, ks * 4 + fq)];
#pragma unroll
      for (int nf = 0; nf < 4; ++nf)
        s[nf] = __builtin_amdgcn_mfma_f32_16x16x32_bf16(qf[ks], kf[nf], s[nf], 0, 0, 0);
    }

#pragma unroll
    for (int nf = 0; nf < 4; ++nf)
#pragma unroll
      for (int r = 0; r < 4; ++r) {
        const float p = __expf(s[nf][r] * (float)mfr[nf].h[r]);
        psum[r] += p;
        const int pp = fq * 4 + r, e = nf * 16 + fr;
        PLw[pp * 64 + ((((e >> 3) ^ (pp & 7))) << 3) + (e & 7)] = (bf16_t)p;
      }

#pragma unroll
    for (int ks = 0; ks < 2; ++ks) {
      bf16x8 pf = *(const bf16x8*)&PLw[swz(fr, ks * 4 + fq)];
      bf16x8 vf[4];
#pragma unroll
      for (int nfo = 0; nfo < 4; ++nfo)
        vf[nfo] = *(const bf16x8*)&Vs[swz(nfo * 16 + fr, ks * 4 + fq)];
#pragma unroll
      for (int nfo = 0; nfo < 4; ++nfo)
        o[nfo] = __builtin_amdgcn_mfma_f32_16x16x32_bf16(pf, vf[nfo], o[nfo], 0, 0, 0);
    }
  }

#pragma unroll
  for (int r = 0; r < 4; ++r) {
    psum[r] += __shfl_xor(psum[r], 1);
    psum[r] += __shfl_xor(psum[r], 2);
    psum[r] += __shfl_xor(psum[r], 4);
    psum[r] += __shfl_xor(psum[r], 8);
  }
#pragma unroll
  for (int r = 0; r < 4; ++r) {
    const int tok = n0 + w * 16 + fq * 4 + r;
    const float inv = 1.f / psum[r];
#pragma unroll
    for (int nfo = 0; nfo < 4; ++nfo)
      aout[((size_t)(bb << 10) + tok) * 512 + hh * 64 + nfo * 16 + fr] = (bf16_t)(o[nfo][r] * inv);
  }
}

// ---------------- launcher ----------------
extern "C" void kernel_launch(void* const* d_in, const int* in_sizes, int n_in,
                              void* d_out, int out_size, void* d_ws, size_t ws_size,
                              hipStream_t stream) {
  (void)in_sizes; (void)n_in; (void)out_size;
  const float* x        = (const float*)d_in[0];
  const float* adj      = (const float*)d_in[1];
  const float* qkv_w    = (const float*)d_in[2];
  const float* proj_w   = (const float*)d_in[3];
  const float* proj_b   = (const float*)d_in[4];
  const float* gat_W    = (const float*)d_in[5];
  const float* gat_Wb   = (const float*)d_in[6];
  const float* gat_ai   = (const float*)d_in[7];
  const float* gat_ai_b = (const float*)d_in[8];
  const float* gat_aj   = (const float*)d_in[9];
  const float* gat_aj_b = (const float*)d_in[10];
  const float* out_W    = (const float*)d_in[11];
  const float* out_Wb   = (const float*)d_in[12];
  const float* out_ai   = (const float*)d_in[13];
  const float* out_ai_b = (const float*)d_in[14];
  const float* out_aj   = (const float*)d_in[15];
  const float* out_aj_b = (const float*)d_in[16];

  char* p = (char*)d_ws;
  auto alloc = [&](size_t bytes) { char* r = p; p += (bytes + 255) & ~(size_t)255; return r; };
  bf16_t* xb     = (bf16_t*)alloc(8192ull * 512 * 2);
  bf16_t* qkvwb  = (bf16_t*)alloc(1536ull * 512 * 2);
  bf16_t* gatwb  = (bf16_t*)alloc(3072ull * 512 * 2);
  bf16_t* outwb  = (bf16_t*)alloc(512ull * 3072 * 2);
  bf16_t* projwb = (bf16_t*)alloc(512ull * 512 * 2);
  bf16_t* qb     = (bf16_t*)alloc(8ull * 8 * 1024 * 64 * 2);
  bf16_t* kb     = (bf16_t*)alloc(8ull * 8 * 1024 * 64 * 2);
  bf16_t* vT     = (bf16_t*)alloc(8ull * 8 * 64 * 1024 * 2);
  float*  Who    = (float*)alloc(8192ull * 512 * 4);   // fallback only
  float*  wv     = (float*)alloc(6 * 512 * 4);
  float*  con    = (float*)alloc(256);
  float*  ev     = (float*)alloc(6 * 8192 * 4);
  float*  eo1    = (float*)alloc(8192 * 4);
  float*  eo2    = (float*)alloc(8192 * 4);
  float*  peo    = (float*)alloc(2ull * 393216 * 4);   // [2][24][16][1024] partials
  // zero-init region: wvo, conO (atomic targets)
  float*  wvo    = (float*)alloc(2 * 3072 * 4);
  float*  conO   = (float*)alloc(256);
  const size_t zspan = (size_t)((char*)conO - (char*)wvo) + 256;

  const bool big = ws_size >= 211000000ull;

  const dim3 blk(256);
  k_cast5<<<8192, blk, 0, stream>>>(x, xb, 1048576, qkv_w, qkvwb, 1245184, gat_W, gatwb, 1638400,
                                    out_W, outwb, 2031616, proj_w, projwb, 2097152);
  hipMemsetAsync(wvo, 0, zspan, stream);
  k_wvec<<<dim3(8, 6), blk, 0, stream>>>(gatwb, gat_Wb, gat_ai, gat_ai_b, gat_aj, gat_aj_b, wv, con);
  k_wvec_o<<<dim3(12, 8), blk, 0, stream>>>(out_W, out_Wb, out_ai, out_aj, wvo, conO);
  k_e12v<<<2048, blk, 0, stream>>>(xb, wv, con, ev);
  k_qkv<<<dim3(12, 64), blk, 0, stream>>>(xb, qkvwb, qb, kb, vT);

  if (big) {
    bf16_t* WhT3 = (bf16_t*)alloc(3ull * 8 * 1024 * 1024 * 2);
    bf16_t* att3 = (bf16_t*)alloc(3ull * 8 * 1024 * 1024 * 2);
    bf16_t* mask  = att3;
    bf16_t* maskT = att3 + 8388608;
    bf16_t* aoutb = att3 + 2 * 8388608;

    k_wh<<<dim3(8, 64, 3), blk, 0, stream>>>(xb, gatwb, gat_Wb, WhT3);
    k_gat_att3<<<2048, blk, 0, stream>>>(adj, ev, att3);
    k_hhat256<<<dim3(4, 4, 24), dim3(512), 0, stream>>>(att3, WhT3, wvo, peo);
    k_eored<<<32, blk, 0, stream>>>(peo, eo1, eo2);
    k_mask<<<2048, blk, 0, stream>>>(adj, eo1, eo2, conO, out_ai_b, out_aj_b, mask);
    k_mtr<<<dim3(16, 16, 8), blk, 0, stream>>>(mask, maskT);
    k_flash<<<dim3(16, 8, 8), blk, 0, stream>>>(qb, kb, vT, maskT, aoutb);
    k_lin<<<dim3(4, 64), blk, 0, stream>>>(aoutb, 512, projwb, 512, proj_b, (float*)d_out);
  } else {
    bf16_t* WhT   = (bf16_t*)alloc(8ull * 1024 * 1024 * 2);
    bf16_t* att   = (bf16_t*)alloc(8ull * 1024 * 1024 * 2);
    bf16_t* hh    = (bf16_t*)alloc(8192ull * 1024 * 2);
    bf16_t* aoutb = (bf16_t*)alloc(8192ull * 512 * 2);
    bf16_t* maskT = (bf16_t*)alloc(8ull * 1024 * 1024 * 2);
    bf16_t* mask  = att;

    for (int l = 0; l < 3; ++l) {
      k_wh<<<dim3(8, 64, 1), blk, 0, stream>>>(xb, gatwb + (size_t)l * 524288, gat_Wb + l * 1024, WhT);
      k_gat_att<<<8192, blk, 0, stream>>>(adj, ev + (size_t)l * 16384, att);
      k_hhat<<<dim3(8, 8, 8), blk, 0, stream>>>(att, WhT, hh, 1024);
      k_who_acc<<<dim3(4, 64), blk, 0, stream>>>(hh, outwb + l * 1024, out_Wb, Who, l);
    }
    k_eo<<<2048, blk, 0, stream>>>(Who, out_ai, out_aj, eo1, eo2);
    k_mask<<<2048, blk, 0, stream>>>(adj, eo1, eo2, conO, out_ai_b, out_aj_b, mask);
    k_mtr<<<dim3(16, 16, 8), blk, 0, stream>>>(mask, maskT);
    k_flash<<<dim3(16, 8, 8), blk, 0, stream>>>(qb, kb, vT, maskT, aoutb);
    k_lin<<<dim3(4, 64), blk, 0, stream>>>(aoutb, 512, projwb, 512, proj_b, (float*)d_out);
  }
}

// Round 14
// 267.395 us; speedup vs baseline: 1.0512x; 1.0262x over previous
//
#include <hip/hip_runtime.h>
#include <math.h>
#include <stdint.h>

#define SCALEQ 0.125f

typedef __bf16 bf16_t;
typedef __bf16 bf16x8 __attribute__((ext_vector_type(8)));
typedef float f32x4 __attribute__((ext_vector_type(4)));

// global -> LDS async copy, 16B per lane. LDS dest is wave-uniform base + lane*16.
#define GLOAD_LDS16(gsrc, ldst)                                                   \
  __builtin_amdgcn_global_load_lds(                                               \
      (const __attribute__((address_space(1))) void*)(uintptr_t)(const void*)(gsrc), \
      (__attribute__((address_space(3))) void*)(uintptr_t)(void*)(ldst), 16, 0, 0)

// XCD-chunked bijective block swizzle (grid total must be %8==0).
__device__ __forceinline__ int3 xswz3() {
  const int nx = gridDim.x, ny = gridDim.y;
  int lin = (blockIdx.z * ny + blockIdx.y) * nx + blockIdx.x;
  const int n = nx * ny * gridDim.z;
  int work = (lin & 7) * (n >> 3) + (lin >> 3);
  int3 r;
  r.x = work % nx; work /= nx;
  r.y = work % ny; r.z = work / ny;
  return r;
}

// ---------------- bf16 MFMA GEMM core (128x128 tile, 4 waves, BK=64) ----------------
// Rule-#21 XOR swizzle: linear LDS dest, per-lane global SOURCE chunk permuted,
// reads apply the same involution (verified: SQ_LDS_BANK_CONFLICT == 0).
__device__ __forceinline__ void mm_bf16(const bf16_t* __restrict__ A, int lda,
                                        const bf16_t* __restrict__ B, int ldb,
                                        int K, int m0, int n0,
                                        bf16_t* As, bf16_t* Bs, f32x4 (&acc)[4][4]) {
  const int tid = threadIdx.x, lane = tid & 63, w = tid >> 6;
  const int wr = (w >> 1) * 64, wc = (w & 1) * 64;
  const int fr = lane & 15, fq = lane >> 4;
  const int c8 = (((lane & 7) ^ ((lane >> 3) & 7)) * 8);   // swizzled source chunk
  for (int kt = 0; kt < K; kt += 64) {
    __syncthreads();
#pragma unroll
    for (int t = 0; t < 4; ++t) {
      const int rl = t * 32 + w * 8 + (lane >> 3);
      GLOAD_LDS16(A + (size_t)(m0 + rl) * lda + kt + c8, As + (t * 32 + w * 8) * 64);
      GLOAD_LDS16(B + (size_t)(n0 + rl) * ldb + kt + c8, Bs + (t * 32 + w * 8) * 64);
    }
    __syncthreads();
#pragma unroll
    for (int ks = 0; ks < 2; ++ks) {
      bf16x8 af[4], bfv[4];
      const int ch = (((ks * 4 + fq) ^ (fr & 7)) << 3);
#pragma unroll
      for (int mf = 0; mf < 4; ++mf)
        af[mf] = *(const bf16x8*)(As + (wr + mf * 16 + fr) * 64 + ch);
#pragma unroll
      for (int nf = 0; nf < 4; ++nf)
        bfv[nf] = *(const bf16x8*)(Bs + (wc + nf * 16 + fr) * 64 + ch);
#pragma unroll
      for (int mf = 0; mf < 4; ++mf)
#pragma unroll
        for (int nf = 0; nf < 4; ++nf)
          acc[mf][nf] = __builtin_amdgcn_mfma_f32_16x16x32_bf16(af[mf], bfv[nf], acc[mf][nf], 0, 0, 0);
    }
  }
}

#define MM_PROLOGUE()                                  \
  __shared__ __align__(16) bf16_t As[128 * 64];        \
  __shared__ __align__(16) bf16_t Bs[128 * 64];        \
  f32x4 acc[4][4];                                     \
  _Pragma("unroll") for (int i_ = 0; i_ < 4; ++i_)     \
  _Pragma("unroll") for (int j_ = 0; j_ < 4; ++j_) acc[i_][j_] = (f32x4)0.0f;

#define MM_EPI_SETUP(M0, N0)                                   \
  const int lane = threadIdx.x & 63, w = threadIdx.x >> 6;     \
  const int fr = lane & 15, fq = lane >> 4;                    \
  const int mb = (M0) + (w >> 1) * 64, nb = (N0) + (w & 1) * 64;

// ---------------- GEMM kernels ----------------
__global__ __launch_bounds__(256) void k_qkv(const bf16_t* __restrict__ xb, const bf16_t* __restrict__ wb,
                                             bf16_t* __restrict__ qb, bf16_t* __restrict__ kb,
                                             bf16_t* __restrict__ vT) {
  MM_PROLOGUE();
  const int3 bi = xswz3();
  const int m0 = bi.y * 128, n0 = bi.x * 128;
  mm_bf16(xb, 512, wb, 512, 512, m0, n0, As, Bs, acc);
  MM_EPI_SETUP(m0, n0);
#pragma unroll
  for (int mf = 0; mf < 4; ++mf)
#pragma unroll
    for (int nf = 0; nf < 4; ++nf) {
      const int n = nb + nf * 16 + fr;
      const int which = n >> 9, hd = (n >> 6) & 7, d = n & 63;
      const int m_ = mb + mf * 16 + fq * 4;
      const int b = m_ >> 10, tok0 = m_ & 1023;
      if (which == 2) {
        union { ushort4 u; bf16_t q[4]; } pk;
#pragma unroll
        for (int r = 0; r < 4; ++r) pk.q[r] = (bf16_t)acc[mf][nf][r];
        *(ushort4*)(vT + (((size_t)b * 8 + hd) * 64 + d) * 1024 + tok0) = pk.u;
      } else {
        bf16_t* dst = which ? kb : qb;
        const float sc = which ? 1.f : SCALEQ;
#pragma unroll
        for (int r = 0; r < 4; ++r)
          dst[(((size_t)b * 8 + hd) * 1024 + tok0 + r) * 64 + d] = (bf16_t)(acc[mf][nf][r] * sc);
      }
    }
}

__global__ __launch_bounds__(256) void k_wh(const bf16_t* __restrict__ xb, const bf16_t* __restrict__ gatw,
                                            const float* __restrict__ gWb, bf16_t* __restrict__ WhT) {
  MM_PROLOGUE();
  const int3 bi = xswz3();
  const int m0 = bi.y * 128, n0 = bi.x * 128, l = bi.z;
  const bf16_t* Wl = gatw + (size_t)l * 524288;
  const float* Wb = gWb + l * 1024;
  bf16_t* out = WhT + (size_t)l * 8388608;
  mm_bf16(xb, 512, Wl, 512, 512, m0, n0, As, Bs, acc);
  MM_EPI_SETUP(m0, n0);
#pragma unroll
  for (int mf = 0; mf < 4; ++mf)
#pragma unroll
    for (int nf = 0; nf < 4; ++nf) {
      const int h = nb + nf * 16 + fr;
      const float bias = Wb[h];
      const int m_ = mb + mf * 16 + fq * 4;
      const int b = m_ >> 10, ml = m_ & 1023;
      union { ushort4 u; bf16_t q[4]; } pk;
#pragma unroll
      for (int r = 0; r < 4; ++r) pk.q[r] = (bf16_t)(acc[mf][nf][r] + bias);
      *(ushort4*)(out + (((size_t)b << 10) + h) * 1024 + ml) = pk.u;
    }
}

// ---- 256Mx128N tile, 8 waves (4Mw x 2Nw), double-buffered issue-early hhat ----
// grid (8,4,24) = 768 blocks = exactly 3 dispatch waves at 1 block/CU (no tail).
// LDS 96 KB: LA 2x32KB, LB 2x16KB. Fused eo-dot epilogue into
// peo[2][24][16][1024]; slice = prob*16 + bi.x*2 + (w&1), each slot written once.
__global__ __launch_bounds__(512) void k_hhat256(const bf16_t* __restrict__ att, const bf16_t* __restrict__ WhT,
                                                 const float* __restrict__ wvo, float* __restrict__ peo) {
  __shared__ __align__(16) bf16_t LA[2][256 * 64];
  __shared__ __align__(16) bf16_t LB[2][128 * 64];
  const int tid = threadIdx.x, lane = tid & 63, w = tid >> 6;   // w 0..7
  const int fr = lane & 15, fq = lane >> 4;
  const int3 bi = xswz3();
  const int prob = bi.z, l = prob >> 3;
  const size_t off = ((size_t)prob) << 20;
  const bf16_t* A = att + off;
  const bf16_t* B = WhT + off;
  const int m0 = bi.y * 256, n0 = bi.x * 128;
  const int sr8 = w * 8 + (lane >> 3);                          // base row (mod-8 == lane>>3)
  const int c8 = (((lane & 7) ^ ((lane >> 3) & 7)) * 8);        // swizzled source chunk

  f32x4 acc[4][4];
#pragma unroll
  for (int mf = 0; mf < 4; ++mf)
#pragma unroll
    for (int nf = 0; nf < 4; ++nf) acc[mf][nf] = (f32x4)0.0f;

  // prologue: stage tile 0 into buf 0
  {
#pragma unroll
    for (int u = 0; u < 4; ++u)
      GLOAD_LDS16(A + (size_t)(m0 + sr8 + u * 64) * 1024 + c8, &LA[0][(w * 8 + u * 64) * 64]);
#pragma unroll
    for (int u = 0; u < 2; ++u)
      GLOAD_LDS16(B + (size_t)(n0 + sr8 + u * 64) * 1024 + c8, &LB[0][(w * 8 + u * 64) * 64]);
  }
  __syncthreads();   // drains vmcnt(0): buf0 ready

  const int wrow = (w >> 1) * 64, wcol = (w & 1) * 64;
  for (int t = 0; t < 16; ++t) {
    const int cur = t & 1;
    if (t < 15) {      // issue next tile early; lands under this tile's MFMAs
      const int kofs = (t + 1) * 64 + c8;
#pragma unroll
      for (int u = 0; u < 4; ++u)
        GLOAD_LDS16(A + (size_t)(m0 + sr8 + u * 64) * 1024 + kofs, &LA[cur ^ 1][(w * 8 + u * 64) * 64]);
#pragma unroll
      for (int u = 0; u < 2; ++u)
        GLOAD_LDS16(B + (size_t)(n0 + sr8 + u * 64) * 1024 + kofs, &LB[cur ^ 1][(w * 8 + u * 64) * 64]);
    }
    const bf16_t* la = &LA[cur][0];
    const bf16_t* lb = &LB[cur][0];
#pragma unroll
    for (int ks = 0; ks < 2; ++ks) {
      const int ch = (((ks * 4 + fq) ^ (fr & 7)) << 3);
      bf16x8 af[4], bfv[4];
#pragma unroll
      for (int mf = 0; mf < 4; ++mf)
        af[mf] = *(const bf16x8*)(la + (wrow + mf * 16 + fr) * 64 + ch);
#pragma unroll
      for (int nf = 0; nf < 4; ++nf)
        bfv[nf] = *(const bf16x8*)(lb + (wcol + nf * 16 + fr) * 64 + ch);
#pragma unroll
      for (int mf = 0; mf < 4; ++mf)
#pragma unroll
        for (int nf = 0; nf < 4; ++nf)
          acc[mf][nf] = __builtin_amdgcn_mfma_f32_16x16x32_bf16(af[mf], bfv[nf], acc[mf][nf], 0, 0, 0);
    }
    __syncthreads();   // everyone done reading buf[cur]; next tile's loads drained
  }

  // fused eo-dot epilogue (f32 pre-rounding elu values)
  float w1[4], w2[4];
#pragma unroll
  for (int nf = 0; nf < 4; ++nf) {
    const int n = n0 + wcol + nf * 16 + fr;
    w1[nf] = wvo[l * 1024 + n];
    w2[nf] = wvo[3072 + l * 1024 + n];
  }
  float* p1 = peo + (((size_t)prob * 16) + bi.x * 2 + (w & 1)) * 1024;
  float* p2 = p1 + 393216;   // 24*16*1024
#pragma unroll
  for (int mf = 0; mf < 4; ++mf)
#pragma unroll
    for (int r = 0; r < 4; ++r) {
      float s1 = 0.f, s2 = 0.f;
#pragma unroll
      for (int nf = 0; nf < 4; ++nf) {
        float v = acc[mf][nf][r];
        v = v > 0.f ? v : (__expf(v) - 1.f);
        s1 = fmaf(v, w1[nf], s1);
        s2 = fmaf(v, w2[nf], s2);
      }
      s1 += __shfl_xor(s1, 1); s1 += __shfl_xor(s1, 2); s1 += __shfl_xor(s1, 4); s1 += __shfl_xor(s1, 8);
      s2 += __shfl_xor(s2, 1); s2 += __shfl_xor(s2, 2); s2 += __shfl_xor(s2, 4); s2 += __shfl_xor(s2, 8);
      if (fr == 0) {
        const int rowloc = m0 + wrow + mf * 16 + fq * 4 + r;   // 0..1023
        p1[rowloc] = s1;
        p2[rowloc] = s2;
      }
    }
}

// fallback-path hhat (128^2): writes hh
__global__ __launch_bounds__(256) void k_hhat(const bf16_t* __restrict__ att, const bf16_t* __restrict__ WhT,
                                              bf16_t* __restrict__ hh, int ldh) {
  MM_PROLOGUE();
  const int3 bi = xswz3();
  const int m0 = bi.y * 128, n0 = bi.x * 128;
  const int prob = bi.z;
  const int l = prob >> 3, bz = prob & 7;
  const size_t off = ((size_t)prob) << 20;
  mm_bf16(att + off, 1024, WhT + off, 1024, 1024, m0, n0, As, Bs, acc);
  MM_EPI_SETUP(m0, n0);
#pragma unroll
  for (int mf = 0; mf < 4; ++mf)
#pragma unroll
    for (int nf = 0; nf < 4; ++nf) {
      const int n = nb + nf * 16 + fr;
#pragma unroll
      for (int r = 0; r < 4; ++r) {
        const int m = mb + mf * 16 + fq * 4 + r;
        float v = acc[mf][nf][r];
        v = v > 0.f ? v : (__expf(v) - 1.f);
        hh[(size_t)((bz << 10) + m) * ldh + l * 1024 + n] = (bf16_t)v;
      }
    }
}

// reduce peo partials -> eo1/eo2 (raw sums; constants added in k_mask)
__global__ __launch_bounds__(256) void k_eored(const float* __restrict__ peo,
                                               float* __restrict__ eo1, float* __restrict__ eo2) {
  const int m = blockIdx.x * 256 + threadIdx.x;   // 0..8191
  const int b = m >> 10, r = m & 1023;
  float s1 = 0.f, s2 = 0.f;
#pragma unroll
  for (int l = 0; l < 3; ++l)
#pragma unroll
    for (int s = 0; s < 16; ++s) {
      const size_t idx = (((size_t)(l * 8 + b)) * 16 + s) * 1024 + r;
      s1 += peo[idx];
      s2 += peo[393216 + idx];
    }
  eo1[m] = s1;
  eo2[m] = s2;
}

__global__ __launch_bounds__(256) void k_lin(const bf16_t* __restrict__ A, int lda,
                                             const bf16_t* __restrict__ B, int K,
                                             const float* __restrict__ bias, float* __restrict__ out) {
  MM_PROLOGUE();
  const int3 bi = xswz3();
  const int m0 = bi.y * 128, n0 = bi.x * 128;
  mm_bf16(A, lda, B, K, K, m0, n0, As, Bs, acc);
  MM_EPI_SETUP(m0, n0);
#pragma unroll
  for (int mf = 0; mf < 4; ++mf)
#pragma unroll
    for (int nf = 0; nf < 4; ++nf) {
      const int n = nb + nf * 16 + fr;
#pragma unroll
      for (int r = 0; r < 4; ++r) {
        const int m = mb + mf * 16 + fq * 4 + r;
        out[(size_t)m * 512 + n] = acc[mf][nf][r] + bias[n];
      }
    }
}

// fallback: Who (+)= hh @ out_W[:, l*1024:+1024].T (bias folded at l==0)
__global__ __launch_bounds__(256) void k_who_acc(const bf16_t* __restrict__ hh, const bf16_t* __restrict__ Wl,
                                                 const float* __restrict__ Wb, float* __restrict__ Who, int l) {
  MM_PROLOGUE();
  const int m0 = blockIdx.y * 128, n0 = blockIdx.x * 128;
  mm_bf16(hh, 1024, Wl, 3072, 1024, m0, n0, As, Bs, acc);
  MM_EPI_SETUP(m0, n0);
#pragma unroll
  for (int mf = 0; mf < 4; ++mf)
#pragma unroll
    for (int nf = 0; nf < 4; ++nf) {
      const int n = nb + nf * 16 + fr;
#pragma unroll
      for (int r = 0; r < 4; ++r) {
        const int m = mb + mf * 16 + fq * 4 + r;
        const size_t idx = (size_t)m * 512 + n;
        Who[idx] = acc[mf][nf][r] + (l == 0 ? Wb[n] : Who[idx]);
      }
    }
}

// ---------------- fused casts f32 -> bf16 (5 segments) ----------------
__global__ __launch_bounds__(256) void k_cast5(const float* __restrict__ s0, bf16_t* __restrict__ d0, int c0,
                                               const float* __restrict__ s1, bf16_t* __restrict__ d1, int c1,
                                               const float* __restrict__ s2, bf16_t* __restrict__ d2, int c2,
                                               const float* __restrict__ s3, bf16_t* __restrict__ d3, int c3,
                                               const float* __restrict__ s4, bf16_t* __restrict__ d4, int c4) {
  int i = blockIdx.x * 256 + threadIdx.x;
  const float* src; bf16_t* dst; int j;
  if (i < c0)      { src = s0; dst = d0; j = i; }
  else if (i < c1) { src = s1; dst = d1; j = i - c0; }
  else if (i < c2) { src = s2; dst = d2; j = i - c1; }
  else if (i < c3) { src = s3; dst = d3; j = i - c2; }
  else if (i < c4) { src = s4; dst = d4; j = i - c3; }
  else return;
  float4 v = ((const float4*)src)[j];
  union { ushort4 u; bf16_t b[4]; } p;
  p.b[0] = (bf16_t)v.x; p.b[1] = (bf16_t)v.y; p.b[2] = (bf16_t)v.z; p.b[3] = (bf16_t)v.w;
  ((ushort4*)dst)[j] = p.u;
}

// ---------------- algebraic e1/e2 (gat layers) ----------------
__global__ __launch_bounds__(256) void k_wvec(const bf16_t* __restrict__ gatwb,
                                              const float* __restrict__ gWb,
                                              const float* __restrict__ ai, const float* __restrict__ aib,
                                              const float* __restrict__ aj, const float* __restrict__ ajb,
                                              float* __restrict__ wv, float* __restrict__ con) {
  __shared__ float sred[4][64];
  __shared__ float cred[256];
  const int v = blockIdx.y, l = v >> 1;
  const float* avec = ((v & 1) ? aj : ai) + (l << 10);
  const bf16_t* W = gatwb + ((size_t)(l << 10)) * 512;
  const int tid = threadIdx.x, hg = tid >> 6, cc = tid & 63;
  const int c = blockIdx.x * 64 + cc;
  float p = 0.f;
  for (int i = 0; i < 256; ++i) {
    const int h = hg * 256 + i;
    p = fmaf((float)W[(size_t)h * 512 + c], avec[h], p);
  }
  sred[hg][cc] = p;
  float cp = 0.f;
#pragma unroll
  for (int i = 0; i < 4; ++i) cp = fmaf(gWb[(l << 10) + tid + i * 256], avec[tid + i * 256], cp);
  cred[tid] = cp;
  __syncthreads();
  if (tid < 64) wv[v * 512 + blockIdx.x * 64 + tid] = sred[0][tid] + sred[1][tid] + sred[2][tid] + sred[3][tid];
  for (int s = 128; s > 0; s >>= 1) {
    if (tid < s) cred[tid] += cred[tid + s];
    __syncthreads();
  }
  if (tid == 0 && blockIdx.x == 0) con[v] = cred[0] + ((v & 1) ? ajb[l] : aib[l]);
}

// out-attention vectors: wvo[v][c] = sum_d out_W[d][c]*avec[d]; conO[v] = dot(out_Wb, avec).
__global__ __launch_bounds__(256) void k_wvec_o(const float* __restrict__ W, const float* __restrict__ Wb,
                                                const float* __restrict__ ai, const float* __restrict__ aj,
                                                float* __restrict__ wvo, float* __restrict__ conO) {
  const int c = blockIdx.x * 256 + threadIdx.x;     // 0..3071
  const int d0 = blockIdx.y * 64;                   // 8 chunks of 64
  float s1 = 0.f, s2 = 0.f;
  for (int t = 0; t < 64; ++t) {
    const float w = W[(size_t)(d0 + t) * 3072 + c];
    s1 = fmaf(w, ai[d0 + t], s1);
    s2 = fmaf(w, aj[d0 + t], s2);
  }
  atomicAdd(&wvo[c], s1);
  atomicAdd(&wvo[3072 + c], s2);
  if (blockIdx.x == 0 && threadIdx.x < 64) {
    const int d = d0 + threadIdx.x;
    float c1 = Wb[d] * ai[d], c2 = Wb[d] * aj[d];
#pragma unroll
    for (int off = 32; off > 0; off >>= 1) { c1 += __shfl_xor(c1, off); c2 += __shfl_xor(c2, off); }
    if (threadIdx.x == 0) { atomicAdd(&conO[0], c1); atomicAdd(&conO[1], c2); }
  }
}

__global__ __launch_bounds__(256) void k_e12v(const bf16_t* __restrict__ xb,
                                              const float* __restrict__ wv, const float* __restrict__ con,
                                              float* __restrict__ ev) {
  const int tid = threadIdx.x, lane = tid & 63, wid = tid >> 6;
  const int row = blockIdx.x * 4 + wid;
  bf16x8 xv = *(const bf16x8*)(xb + (size_t)row * 512 + lane * 8);
  float xf[8];
#pragma unroll
  for (int j = 0; j < 8; ++j) xf[j] = (float)xv[j];
  float s[6];
#pragma unroll
  for (int v = 0; v < 6; ++v) {
    const float* wp = wv + v * 512 + lane * 8;
    float a = 0.f;
#pragma unroll
    for (int j = 0; j < 8; ++j) a = fmaf(xf[j], wp[j], a);
    s[v] = a;
  }
#pragma unroll
  for (int v = 0; v < 6; ++v)
#pragma unroll
    for (int off = 32; off > 0; off >>= 1) s[v] += __shfl_xor(s[v], off);
  if (lane == 0) {
#pragma unroll
    for (int v = 0; v < 6; ++v) ev[v * 8192 + row] = s[v] + con[v];
  }
}

// fallback: raw row-dots (constants added in k_mask)
__global__ __launch_bounds__(256) void k_eo(const float* __restrict__ Who,
                                            const float* __restrict__ ai, const float* __restrict__ aj,
                                            float* __restrict__ eo1, float* __restrict__ eo2) {
  const int wid = threadIdx.x >> 6, lane = threadIdx.x & 63;
  const int row = blockIdx.x * 4 + wid;
  const float* wr = Who + (size_t)row * 512;
  float s1 = 0.f, s2 = 0.f;
#pragma unroll
  for (int c = 0; c < 2; ++c) {
    const int idx = c * 256 + lane * 4;
    float4 w4 = *(const float4*)&wr[idx];
    float4 a4 = *(const float4*)&ai[idx];
    float4 b4 = *(const float4*)&aj[idx];
    s1 += w4.x * a4.x + w4.y * a4.y + w4.z * a4.z + w4.w * a4.w;
    s2 += w4.x * b4.x + w4.y * b4.y + w4.z * b4.z + w4.w * b4.w;
  }
#pragma unroll
  for (int off = 32; off > 0; off >>= 1) { s1 += __shfl_xor(s1, off); s2 += __shfl_xor(s2, off); }
  if (lane == 0) { eo1[row] = s1; eo2[row] = s2; }
}

// ---------------- block reduce helpers (fallback kernels) ----------------
__device__ __forceinline__ float block_max(float v, float* red) {
#pragma unroll
  for (int off = 32; off > 0; off >>= 1) v = fmaxf(v, __shfl_xor(v, off));
  __syncthreads();
  if ((threadIdx.x & 63) == 0) red[threadIdx.x >> 6] = v;
  __syncthreads();
  return fmaxf(fmaxf(red[0], red[1]), fmaxf(red[2], red[3]));
}
__device__ __forceinline__ float block_sum(float v, float* red) {
#pragma unroll
  for (int off = 32; off > 0; off >>= 1) v += __shfl_xor(v, off);
  __syncthreads();
  if ((threadIdx.x & 63) == 0) red[threadIdx.x >> 6] = v;
  __syncthreads();
  return red[0] + red[1] + red[2] + red[3];
}

// ---------------- GAT attention rows: wave-per-row, all 3 layers, no barriers ----------------
__global__ __launch_bounds__(256) void k_gat_att3(const float* __restrict__ adj, const float* __restrict__ ev,
                                                  bf16_t* __restrict__ att) {
  const int lane = threadIdx.x & 63;
  const int row = blockIdx.x * 4 + (threadIdx.x >> 6);
  const int b = row >> 10;
  const float* arow = adj + (size_t)row * 1024;
  float a[4][4];
#pragma unroll
  for (int c = 0; c < 4; ++c) *(float4*)a[c] = *(const float4*)&arow[(c * 64 + lane) * 4];
#pragma unroll
  for (int l = 0; l < 3; ++l) {
    const float e1v = ev[l * 16384 + row];
    const float* e2r = ev + l * 16384 + 8192 + (b << 10);
    bf16_t* aout = att + (size_t)l * 8388608 + (size_t)row * 1024;
    float s[4][4];
    float mx = -1e30f;
#pragma unroll
    for (int c = 0; c < 4; ++c) {
      float4 e4 = *(const float4*)&e2r[(c * 64 + lane) * 4];
      float ee[4] = {e4.x, e4.y, e4.z, e4.w};
#pragma unroll
      for (int j = 0; j < 4; ++j) {
        float e = e1v + ee[j];
        e = e > 0.f ? e : 0.2f * e;
        s[c][j] = a[c][j] * e;
        mx = fmaxf(mx, s[c][j]);
      }
    }
#pragma unroll
    for (int off = 32; off > 0; off >>= 1) mx = fmaxf(mx, __shfl_xor(mx, off));
    float sum = 0.f;
#pragma unroll
    for (int c = 0; c < 4; ++c)
#pragma unroll
      for (int j = 0; j < 4; ++j) { float p = __expf(s[c][j] - mx); s[c][j] = p; sum += p; }
#pragma unroll
    for (int off = 32; off > 0; off >>= 1) sum += __shfl_xor(sum, off);
    const float inv = 1.f / sum;
#pragma unroll
    for (int c = 0; c < 4; ++c) {
      union { ushort4 u; bf16_t q[4]; } pk;
#pragma unroll
      for (int j = 0; j < 4; ++j) pk.q[j] = (bf16_t)(s[c][j] * inv);
      *(ushort4*)(aout + (c * 64 + lane) * 4) = pk.u;
    }
  }
}

// fallback single-layer version (block-per-row)
__global__ __launch_bounds__(256) void k_gat_att(const float* __restrict__ adj, const float* __restrict__ ev,
                                                 bf16_t* __restrict__ att) {
  __shared__ float red[4];
  const int row = blockIdx.x;
  const int b = row >> 10;
  const float* arow = adj + (size_t)row * 1024;
  const float e1v = ev[row];
  const float* e2r = ev + 8192 + (b << 10);
  float s[4];
  float mx = -1e30f;
#pragma unroll
  for (int c = 0; c < 4; ++c) {
    const int m = c * 256 + threadIdx.x;
    float e = e1v + e2r[m];
    e = e > 0.f ? e : 0.2f * e;
    s[c] = arow[m] * e;
    mx = fmaxf(mx, s[c]);
  }
  mx = block_max(mx, red);
  float sum = 0.f;
#pragma unroll
  for (int c = 0; c < 4; ++c) { float p = __expf(s[c] - mx); s[c] = p; sum += p; }
  sum = block_sum(sum, red);
  const float inv = 1.f / sum;
#pragma unroll
  for (int c = 0; c < 4; ++c) att[(size_t)row * 1024 + c * 256 + threadIdx.x] = (bf16_t)(s[c] * inv);
}

// ---------------- output-attention mask: wave-per-row double softmax ----------------
__global__ __launch_bounds__(256) void k_mask(const float* __restrict__ adj, const float* __restrict__ eo1,
                                              const float* __restrict__ eo2, const float* __restrict__ conO,
                                              const float* __restrict__ aib, const float* __restrict__ ajb,
                                              bf16_t* __restrict__ mask) {
  const int lane = threadIdx.x & 63;
  const int row = blockIdx.x * 4 + (threadIdx.x >> 6);
  const int b = row >> 10;
  const float* arow = adj + (size_t)row * 1024;
  const float t1 = eo1[row] + conO[0] + aib[0];
  const float c2 = conO[1] + ajb[0];
  const float* eor = eo2 + (b << 10);
  float s[4][4];
  float mx = -1e30f;
#pragma unroll
  for (int c = 0; c < 4; ++c) {
    float4 a4 = *(const float4*)&arow[(c * 64 + lane) * 4];
    float4 e4 = *(const float4*)&eor[(c * 64 + lane) * 4];
    float aa[4] = {a4.x, a4.y, a4.z, a4.w};
    float ee[4] = {e4.x, e4.y, e4.z, e4.w};
#pragma unroll
    for (int j = 0; j < 4; ++j) {
      float e = t1 + ee[j] + c2;
      e = e > 0.f ? e : 0.2f * e;
      s[c][j] = aa[j] * e;
      mx = fmaxf(mx, s[c][j]);
    }
  }
#pragma unroll
  for (int off = 32; off > 0; off >>= 1) mx = fmaxf(mx, __shfl_xor(mx, off));
  float sum = 0.f;
#pragma unroll
  for (int c = 0; c < 4; ++c)
#pragma unroll
    for (int j = 0; j < 4; ++j) { float p = __expf(s[c][j] - mx); s[c][j] = p; sum += p; }
#pragma unroll
  for (int off = 32; off > 0; off >>= 1) sum += __shfl_xor(sum, off);
  const float inv = 1.f / sum;        // == max of first softmax
  float sum2 = 0.f;
#pragma unroll
  for (int c = 0; c < 4; ++c)
#pragma unroll
    for (int j = 0; j < 4; ++j) { float p = __expf(s[c][j] * inv - inv); s[c][j] = p; sum2 += p; }
#pragma unroll
  for (int off = 32; off > 0; off >>= 1) sum2 += __shfl_xor(sum2, off);
  const float inv2 = 1.f / sum2;
#pragma unroll
  for (int c = 0; c < 4; ++c) {
    union { ushort4 u; bf16_t q[4]; } pk;
#pragma unroll
    for (int j = 0; j < 4; ++j) pk.q[j] = (bf16_t)(s[c][j] * inv2);
    *(ushort4*)(mask + (size_t)row * 1024 + (c * 64 + lane) * 4) = pk.u;
  }
}

// ---------------- mask transpose ----------------
__global__ __launch_bounds__(256) void k_mtr(const bf16_t* __restrict__ in, bf16_t* __restrict__ out) {
  __shared__ bf16_t T[64][72];
  const int q0 = blockIdx.x * 64, k0 = blockIdx.y * 64, b = blockIdx.z;
  const bf16_t* src = in + ((size_t)b << 20);
  bf16_t* dst = out + ((size_t)b << 20);
  const int r = threadIdx.x >> 2, c = (threadIdx.x & 3) * 16;
  bf16x8 a0 = *(const bf16x8*)(src + (size_t)(q0 + r) * 1024 + k0 + c);
  bf16x8 a1 = *(const bf16x8*)(src + (size_t)(q0 + r) * 1024 + k0 + c + 8);
  *(bf16x8*)&T[r][c] = a0;
  *(bf16x8*)&T[r][c + 8] = a1;
  __syncthreads();
  union { bf16x8 v[2]; bf16_t e[16]; } o;
#pragma unroll
  for (int j = 0; j < 16; ++j) o.e[j] = T[c + j][r];
  *(bf16x8*)(dst + (size_t)(k0 + r) * 1024 + q0 + c) = o.v[0];
  *(bf16x8*)(dst + (size_t)(k0 + r) * 1024 + q0 + c + 8) = o.v[1];
}

// ---------------- MFMA flash attention (XOR-swizzled K/V + P LDS) ----------------
__device__ __forceinline__ int swz(int row, int slot) { return row * 64 + ((slot ^ (row & 7)) << 3); }

__global__ __launch_bounds__(256) void k_flash(const bf16_t* __restrict__ qg, const bf16_t* __restrict__ kg,
                                               const bf16_t* __restrict__ vTg, const bf16_t* __restrict__ maskT,
                                               bf16_t* __restrict__ aout) {
  __shared__ __align__(16) bf16_t Ks[4096];
  __shared__ __align__(16) bf16_t Vs[4096];
  __shared__ __align__(16) bf16_t PL[4][1024];   // per-wave 16x64, swizzled
  const int tid = threadIdx.x, lane = tid & 63, w = tid >> 6;
  const int fr = lane & 15, fq = lane >> 4;
  const int3 bi = xswz3();
  const int n0 = bi.x * 64, hh = bi.y, bb = bi.z;
  const size_t bh = ((size_t)bb * 8 + hh) << 16;
  const bf16_t* q = qg + bh;
  const bf16_t* kk = kg + bh;
  const bf16_t* vT = vTg + bh;
  const bf16_t* mT = maskT + ((size_t)bb << 20);
  bf16_t* PLw = &PL[w][0];

  bf16x8 qf[2];
#pragma unroll
  for (int ks = 0; ks < 2; ++ks)
    qf[ks] = *(const bf16x8*)(q + (size_t)(n0 + w * 16 + fr) * 64 + ks * 32 + fq * 8);

  f32x4 o[4];
#pragma unroll
  for (int nf = 0; nf < 4; ++nf) o[nf] = (f32x4)0.0f;
  float psum[4] = {0.f, 0.f, 0.f, 0.f};

  const int srow = tid >> 2, sslot = (tid & 3) * 2;
  const int ws0 = swz(srow, sslot), ws1 = swz(srow, sslot + 1);
  const int scol = (tid & 3) * 16;

  for (int c = 0; c < 16; ++c) {
    const int k0 = c * 64;
    bf16x8 kv0 = *(const bf16x8*)(kk + (size_t)(k0 + srow) * 64 + scol);
    bf16x8 kv1 = *(const bf16x8*)(kk + (size_t)(k0 + srow) * 64 + scol + 8);
    bf16x8 vv0 = *(const bf16x8*)(vT + (size_t)srow * 1024 + k0 + scol);
    bf16x8 vv1 = *(const bf16x8*)(vT + (size_t)srow * 1024 + k0 + scol + 8);
    union { ushort4 u; bf16_t h[4]; } mfr[4];
#pragma unroll
    for (int nf = 0; nf < 4; ++nf)
      mfr[nf].u = *(const ushort4*)(mT + (size_t)(k0 + nf * 16 + fr) * 1024 + n0 + w * 16 + fq * 4);
    __syncthreads();
    *(bf16x8*)&Ks[ws0] = kv0; *(bf16x8*)&Ks[ws1] = kv1;
    *(bf16x8*)&Vs[ws0] = vv0; *(bf16x8*)&Vs[ws1] = vv1;
    __syncthreads();

    f32x4 s[4];
#pragma unroll
    for (int nf = 0; nf < 4; ++nf) s[nf] = (f32x4)0.0f;
#pragma unroll
    for (int ks = 0; ks < 2; ++ks) {
      bf16x8 kf[4];
#pragma unroll
      for (int nf = 0; nf < 4; ++nf)
        kf[nf] = *(const bf16x8*)&Ks[swz(nf * 16 + fr, ks * 4 + fq)];
#pragma unroll
      for (int nf = 0; nf < 4; ++nf)
        s[nf] = __builtin_amdgcn_mfma_f32_16x16x32_bf16(qf[ks], kf[nf], s[nf], 0, 0, 0);
    }

#pragma unroll
    for (int nf = 0; nf < 4; ++nf)
#pragma unroll
      for (int r = 0; r < 4; ++r) {
        const float p = __expf(s[nf][r] * (float)mfr[nf].h[r]);
        psum[r] += p;
        const int pp = fq * 4 + r, e = nf * 16 + fr;
        PLw[pp * 64 + ((((e >> 3) ^ (pp & 7))) << 3) + (e & 7)] = (bf16_t)p;
      }

#pragma unroll
    for (int ks = 0; ks < 2; ++ks) {
      bf16x8 pf = *(const bf16x8*)&PLw[swz(fr, ks * 4 + fq)];
      bf16x8 vf[4];
#pragma unroll
      for (int nfo = 0; nfo < 4; ++nfo)
        vf[nfo] = *(const bf16x8*)&Vs[swz(nfo * 16 + fr, ks * 4 + fq)];
#pragma unroll
      for (int nfo = 0; nfo < 4; ++nfo)
        o[nfo] = __builtin_amdgcn_mfma_f32_16x16x32_bf16(pf, vf[nfo], o[nfo], 0, 0, 0);
    }
  }

#pragma unroll
  for (int r = 0; r < 4; ++r) {
    psum[r] += __shfl_xor(psum[r], 1);
    psum[r] += __shfl_xor(psum[r], 2);
    psum[r] += __shfl_xor(psum[r], 4);
    psum[r] += __shfl_xor(psum[r], 8);
  }
#pragma unroll
  for (int r = 0; r < 4; ++r) {
    const int tok = n0 + w * 16 + fq * 4 + r;
    const float inv = 1.f / psum[r];
#pragma unroll
    for (int nfo = 0; nfo < 4; ++nfo)
      aout[((size_t)(bb << 10) + tok) * 512 + hh * 64 + nfo * 16 + fr] = (bf16_t)(o[nfo][r] * inv);
  }
}

// ---------------- launcher ----------------
extern "C" void kernel_launch(void* const* d_in, const int* in_sizes, int n_in,
                              void* d_out, int out_size, void* d_ws, size_t ws_size,
                              hipStream_t stream) {
  (void)in_sizes; (void)n_in; (void)out_size;
  const float* x        = (const float*)d_in[0];
  const float* adj      = (const float*)d_in[1];
  const float* qkv_w    = (const float*)d_in[2];
  const float* proj_w   = (const float*)d_in[3];
  const float* proj_b   = (const float*)d_in[4];
  const float* gat_W    = (const float*)d_in[5];
  const float* gat_Wb   = (const float*)d_in[6];
  const float* gat_ai   = (const float*)d_in[7];
  const float* gat_ai_b = (const float*)d_in[8];
  const float* gat_aj   = (const float*)d_in[9];
  const float* gat_aj_b = (const float*)d_in[10];
  const float* out_W    = (const float*)d_in[11];
  const float* out_Wb   = (const float*)d_in[12];
  const float* out_ai   = (const float*)d_in[13];
  const float* out_ai_b = (const float*)d_in[14];
  const float* out_aj   = (const float*)d_in[15];
  const float* out_aj_b = (const float*)d_in[16];

  char* p = (char*)d_ws;
  auto alloc = [&](size_t bytes) { char* r = p; p += (bytes + 255) & ~(size_t)255; return r; };
  bf16_t* xb     = (bf16_t*)alloc(8192ull * 512 * 2);
  bf16_t* qkvwb  = (bf16_t*)alloc(1536ull * 512 * 2);
  bf16_t* gatwb  = (bf16_t*)alloc(3072ull * 512 * 2);
  bf16_t* outwb  = (bf16_t*)alloc(512ull * 3072 * 2);
  bf16_t* projwb = (bf16_t*)alloc(512ull * 512 * 2);
  bf16_t* qb     = (bf16_t*)alloc(8ull * 8 * 1024 * 64 * 2);
  bf16_t* kb     = (bf16_t*)alloc(8ull * 8 * 1024 * 64 * 2);
  bf16_t* vT     = (bf16_t*)alloc(8ull * 8 * 64 * 1024 * 2);
  float*  Who    = (float*)alloc(8192ull * 512 * 4);   // fallback only
  float*  wv     = (float*)alloc(6 * 512 * 4);
  float*  con    = (float*)alloc(256);
  float*  ev     = (float*)alloc(6 * 8192 * 4);
  float*  eo1    = (float*)alloc(8192 * 4);
  float*  eo2    = (float*)alloc(8192 * 4);
  float*  peo    = (float*)alloc(2ull * 393216 * 4);   // [2][24][16][1024] partials
  // zero-init region: wvo, conO (atomic targets)
  float*  wvo    = (float*)alloc(2 * 3072 * 4);
  float*  conO   = (float*)alloc(256);
  const size_t zspan = (size_t)((char*)conO - (char*)wvo) + 256;

  const bool big = ws_size >= 211000000ull;

  const dim3 blk(256);
  k_cast5<<<8192, blk, 0, stream>>>(x, xb, 1048576, qkv_w, qkvwb, 1245184, gat_W, gatwb, 1638400,
                                    out_W, outwb, 2031616, proj_w, projwb, 2097152);
  hipMemsetAsync(wvo, 0, zspan, stream);
  k_wvec<<<dim3(8, 6), blk, 0, stream>>>(gatwb, gat_Wb, gat_ai, gat_ai_b, gat_aj, gat_aj_b, wv, con);
  k_wvec_o<<<dim3(12, 8), blk, 0, stream>>>(out_W, out_Wb, out_ai, out_aj, wvo, conO);
  k_e12v<<<2048, blk, 0, stream>>>(xb, wv, con, ev);
  k_qkv<<<dim3(12, 64), blk, 0, stream>>>(xb, qkvwb, qb, kb, vT);

  if (big) {
    bf16_t* WhT3 = (bf16_t*)alloc(3ull * 8 * 1024 * 1024 * 2);
    bf16_t* att3 = (bf16_t*)alloc(3ull * 8 * 1024 * 1024 * 2);
    bf16_t* mask  = att3;
    bf16_t* maskT = att3 + 8388608;
    bf16_t* aoutb = att3 + 2 * 8388608;

    k_wh<<<dim3(8, 64, 3), blk, 0, stream>>>(xb, gatwb, gat_Wb, WhT3);
    k_gat_att3<<<2048, blk, 0, stream>>>(adj, ev, att3);
    k_hhat256<<<dim3(8, 4, 24), dim3(512), 0, stream>>>(att3, WhT3, wvo, peo);
    k_eored<<<32, blk, 0, stream>>>(peo, eo1, eo2);
    k_mask<<<2048, blk, 0, stream>>>(adj, eo1, eo2, conO, out_ai_b, out_aj_b, mask);
    k_mtr<<<dim3(16, 16, 8), blk, 0, stream>>>(mask, maskT);
    k_flash<<<dim3(16, 8, 8), blk, 0, stream>>>(qb, kb, vT, maskT, aoutb);
    k_lin<<<dim3(4, 64), blk, 0, stream>>>(aoutb, 512, projwb, 512, proj_b, (float*)d_out);
  } else {
    bf16_t* WhT   = (bf16_t*)alloc(8ull * 1024 * 1024 * 2);
    bf16_t* att   = (bf16_t*)alloc(8ull * 1024 * 1024 * 2);
    bf16_t* hh    = (bf16_t*)alloc(8192ull * 1024 * 2);
    bf16_t* aoutb = (bf16_t*)alloc(8192ull * 512 * 2);
    bf16_t* maskT = (bf16_t*)alloc(8ull * 1024 * 1024 * 2);
    bf16_t* mask  = att;

    for (int l = 0; l < 3; ++l) {
      k_wh<<<dim3(8, 64, 1), blk, 0, stream>>>(xb, gatwb + (size_t)l * 524288, gat_Wb + l * 1024, WhT);
      k_gat_att<<<8192, blk, 0, stream>>>(adj, ev + (size_t)l * 16384, att);
      k_hhat<<<dim3(8, 8, 8), blk, 0, stream>>>(att, WhT, hh, 1024);
      k_who_acc<<<dim3(4, 64), blk, 0, stream>>>(hh, outwb + l * 1024, out_Wb, Who, l);
    }
    k_eo<<<2048, blk, 0, stream>>>(Who, out_ai, out_aj, eo1, eo2);
    k_mask<<<2048, blk, 0, stream>>>(adj, eo1, eo2, conO, out_ai_b, out_aj_b, mask);
    k_mtr<<<dim3(16, 16, 8), blk, 0, stream>>>(mask, maskT);
    k_flash<<<dim3(16, 8, 8), blk, 0, stream>>>(qb, kb, vT, maskT, aoutb);
    k_lin<<<dim3(4, 64), blk, 0, stream>>>(aoutb, 512, projwb, 512, proj_b, (float*)d_out);
  }
}

// Round 15
// 246.616 us; speedup vs baseline: 1.1397x; 1.0843x over previous
//
#include <hip/hip_runtime.h>
#include <math.h>
#include <stdint.h>

#define SCALEQ 0.125f

typedef __bf16 bf16_t;
typedef __bf16 bf16x8 __attribute__((ext_vector_type(8)));
typedef float f32x4 __attribute__((ext_vector_type(4)));

// global -> LDS async copy, 16B per lane. LDS dest is wave-uniform base + lane*16.
#define GLOAD_LDS16(gsrc, ldst)                                                   \
  __builtin_amdgcn_global_load_lds(                                               \
      (const __attribute__((address_space(1))) void*)(uintptr_t)(const void*)(gsrc), \
      (__attribute__((address_space(3))) void*)(uintptr_t)(void*)(ldst), 16, 0, 0)

// XCD-chunked bijective block swizzle (grid total must be %8==0).
__device__ __forceinline__ int3 xswz3() {
  const int nx = gridDim.x, ny = gridDim.y;
  int lin = (blockIdx.z * ny + blockIdx.y) * nx + blockIdx.x;
  const int n = nx * ny * gridDim.z;
  int work = (lin & 7) * (n >> 3) + (lin >> 3);
  int3 r;
  r.x = work % nx; work /= nx;
  r.y = work % ny; r.z = work / ny;
  return r;
}

// ---------------- bf16 MFMA GEMM core (128x128 tile, 4 waves, BK=64) ----------------
// Rule-#21 XOR swizzle: linear LDS dest, per-lane global SOURCE chunk permuted,
// reads apply the same involution (verified: SQ_LDS_BANK_CONFLICT == 0).
__device__ __forceinline__ void mm_bf16(const bf16_t* __restrict__ A, int lda,
                                        const bf16_t* __restrict__ B, int ldb,
                                        int K, int m0, int n0,
                                        bf16_t* As, bf16_t* Bs, f32x4 (&acc)[4][4]) {
  const int tid = threadIdx.x, lane = tid & 63, w = tid >> 6;
  const int wr = (w >> 1) * 64, wc = (w & 1) * 64;
  const int fr = lane & 15, fq = lane >> 4;
  const int c8 = (((lane & 7) ^ ((lane >> 3) & 7)) * 8);   // swizzled source chunk
  for (int kt = 0; kt < K; kt += 64) {
    __syncthreads();
#pragma unroll
    for (int t = 0; t < 4; ++t) {
      const int rl = t * 32 + w * 8 + (lane >> 3);
      GLOAD_LDS16(A + (size_t)(m0 + rl) * lda + kt + c8, As + (t * 32 + w * 8) * 64);
      GLOAD_LDS16(B + (size_t)(n0 + rl) * ldb + kt + c8, Bs + (t * 32 + w * 8) * 64);
    }
    __syncthreads();
#pragma unroll
    for (int ks = 0; ks < 2; ++ks) {
      bf16x8 af[4], bfv[4];
      const int ch = (((ks * 4 + fq) ^ (fr & 7)) << 3);
#pragma unroll
      for (int mf = 0; mf < 4; ++mf)
        af[mf] = *(const bf16x8*)(As + (wr + mf * 16 + fr) * 64 + ch);
#pragma unroll
      for (int nf = 0; nf < 4; ++nf)
        bfv[nf] = *(const bf16x8*)(Bs + (wc + nf * 16 + fr) * 64 + ch);
#pragma unroll
      for (int mf = 0; mf < 4; ++mf)
#pragma unroll
        for (int nf = 0; nf < 4; ++nf)
          acc[mf][nf] = __builtin_amdgcn_mfma_f32_16x16x32_bf16(af[mf], bfv[nf], acc[mf][nf], 0, 0, 0);
    }
  }
}

#define MM_PROLOGUE()                                  \
  __shared__ __align__(16) bf16_t As[128 * 64];        \
  __shared__ __align__(16) bf16_t Bs[128 * 64];        \
  f32x4 acc[4][4];                                     \
  _Pragma("unroll") for (int i_ = 0; i_ < 4; ++i_)     \
  _Pragma("unroll") for (int j_ = 0; j_ < 4; ++j_) acc[i_][j_] = (f32x4)0.0f;

#define MM_EPI_SETUP(M0, N0)                                   \
  const int lane = threadIdx.x & 63, w = threadIdx.x >> 6;     \
  const int fr = lane & 15, fq = lane >> 4;                    \
  const int mb = (M0) + (w >> 1) * 64, nb = (N0) + (w & 1) * 64;

// ---------------- GEMM kernels ----------------
__global__ __launch_bounds__(256) void k_qkv(const bf16_t* __restrict__ xb, const bf16_t* __restrict__ wb,
                                             bf16_t* __restrict__ qb, bf16_t* __restrict__ kb,
                                             bf16_t* __restrict__ vT) {
  MM_PROLOGUE();
  const int3 bi = xswz3();
  const int m0 = bi.y * 128, n0 = bi.x * 128;
  mm_bf16(xb, 512, wb, 512, 512, m0, n0, As, Bs, acc);
  MM_EPI_SETUP(m0, n0);
#pragma unroll
  for (int mf = 0; mf < 4; ++mf)
#pragma unroll
    for (int nf = 0; nf < 4; ++nf) {
      const int n = nb + nf * 16 + fr;
      const int which = n >> 9, hd = (n >> 6) & 7, d = n & 63;
      const int m_ = mb + mf * 16 + fq * 4;
      const int b = m_ >> 10, tok0 = m_ & 1023;
      if (which == 2) {
        union { ushort4 u; bf16_t q[4]; } pk;
#pragma unroll
        for (int r = 0; r < 4; ++r) pk.q[r] = (bf16_t)acc[mf][nf][r];
        *(ushort4*)(vT + (((size_t)b * 8 + hd) * 64 + d) * 1024 + tok0) = pk.u;
      } else {
        bf16_t* dst = which ? kb : qb;
        const float sc = which ? 1.f : SCALEQ;
#pragma unroll
        for (int r = 0; r < 4; ++r)
          dst[(((size_t)b * 8 + hd) * 1024 + tok0 + r) * 64 + d] = (bf16_t)(acc[mf][nf][r] * sc);
      }
    }
}

// fallback-path only: WhT[l][b][h][m]
__global__ __launch_bounds__(256) void k_wh(const bf16_t* __restrict__ xb, const bf16_t* __restrict__ gatw,
                                            const float* __restrict__ gWb, bf16_t* __restrict__ WhT) {
  MM_PROLOGUE();
  const int3 bi = xswz3();
  const int m0 = bi.y * 128, n0 = bi.x * 128, l = bi.z;
  const bf16_t* Wl = gatw + (size_t)l * 524288;
  const float* Wb = gWb + l * 1024;
  bf16_t* out = WhT + (size_t)l * 8388608;
  mm_bf16(xb, 512, Wl, 512, 512, m0, n0, As, Bs, acc);
  MM_EPI_SETUP(m0, n0);
#pragma unroll
  for (int mf = 0; mf < 4; ++mf)
#pragma unroll
    for (int nf = 0; nf < 4; ++nf) {
      const int h = nb + nf * 16 + fr;
      const float bias = Wb[h];
      const int m_ = mb + mf * 16 + fq * 4;
      const int b = m_ >> 10, ml = m_ & 1023;
      union { ushort4 u; bf16_t q[4]; } pk;
#pragma unroll
      for (int r = 0; r < 4; ++r) pk.q[r] = (bf16_t)(acc[mf][nf][r] + bias);
      *(ushort4*)(out + (((size_t)b << 10) + h) * 1024 + ml) = pk.u;
    }
}

// Y[l,b] = att_lb @ x_b  (re-association step A). A=att (lda 1024), B^T=xbT (ldb 1024).
// grid (4, 8, 24) = 768 blocks, 128^2 tile. Y row-major [1024][512] bf16 per problem.
__global__ __launch_bounds__(256) void k_attx(const bf16_t* __restrict__ att, const bf16_t* __restrict__ xbT,
                                              bf16_t* __restrict__ Y) {
  MM_PROLOGUE();
  const int3 bi = xswz3();
  const int m0 = bi.y * 128, n0 = bi.x * 128;
  const int prob = bi.z, b = prob & 7;
  mm_bf16(att + ((size_t)prob << 20), 1024, xbT + (size_t)b * 524288, 1024, 1024, m0, n0, As, Bs, acc);
  MM_EPI_SETUP(m0, n0);
  bf16_t* Yp = Y + (size_t)prob * 524288;
#pragma unroll
  for (int mf = 0; mf < 4; ++mf)
#pragma unroll
    for (int nf = 0; nf < 4; ++nf) {
      const int n = nb + nf * 16 + fr;
#pragma unroll
      for (int r = 0; r < 4; ++r) {
        const int m = mb + mf * 16 + fq * 4 + r;
        Yp[(size_t)m * 512 + n] = (bf16_t)acc[mf][nf][r];
      }
    }
}

// hh = elu(Y @ W_l^T) with fused eo-dot epilogue (re-association step B).
// 256Mx128N tile, 8 waves, double-buffered issue-early, K=512 (8 tiles).
// grid (8,4,24) = 768 blocks = exactly 3 dispatch waves. B^T = gat_W (as stored).
__global__ __launch_bounds__(512) void k_hhatB(const bf16_t* __restrict__ Y, const bf16_t* __restrict__ gatw,
                                               const float* __restrict__ wvo, float* __restrict__ peo) {
  __shared__ __align__(16) bf16_t LA[2][256 * 64];
  __shared__ __align__(16) bf16_t LB[2][128 * 64];
  const int tid = threadIdx.x, lane = tid & 63, w = tid >> 6;   // w 0..7
  const int fr = lane & 15, fq = lane >> 4;
  const int3 bi = xswz3();
  const int prob = bi.z, l = prob >> 3;
  const bf16_t* A = Y + (size_t)prob * 524288;                  // [1024][512]
  const bf16_t* B = gatw + (size_t)l * 524288;                  // [1024][512] = B^T
  const int m0 = bi.y * 256, n0 = bi.x * 128;
  const int sr8 = w * 8 + (lane >> 3);
  const int c8 = (((lane & 7) ^ ((lane >> 3) & 7)) * 8);

  f32x4 acc[4][4];
#pragma unroll
  for (int mf = 0; mf < 4; ++mf)
#pragma unroll
    for (int nf = 0; nf < 4; ++nf) acc[mf][nf] = (f32x4)0.0f;

  // prologue: stage tile 0 into buf 0
  {
#pragma unroll
    for (int u = 0; u < 4; ++u)
      GLOAD_LDS16(A + (size_t)(m0 + sr8 + u * 64) * 512 + c8, &LA[0][(w * 8 + u * 64) * 64]);
#pragma unroll
    for (int u = 0; u < 2; ++u)
      GLOAD_LDS16(B + (size_t)(n0 + sr8 + u * 64) * 512 + c8, &LB[0][(w * 8 + u * 64) * 64]);
  }
  __syncthreads();

  const int wrow = (w >> 1) * 64, wcol = (w & 1) * 64;
  for (int t = 0; t < 8; ++t) {
    const int cur = t & 1;
    if (t < 7) {
      const int kofs = (t + 1) * 64 + c8;
#pragma unroll
      for (int u = 0; u < 4; ++u)
        GLOAD_LDS16(A + (size_t)(m0 + sr8 + u * 64) * 512 + kofs, &LA[cur ^ 1][(w * 8 + u * 64) * 64]);
#pragma unroll
      for (int u = 0; u < 2; ++u)
        GLOAD_LDS16(B + (size_t)(n0 + sr8 + u * 64) * 512 + kofs, &LB[cur ^ 1][(w * 8 + u * 64) * 64]);
    }
    const bf16_t* la = &LA[cur][0];
    const bf16_t* lb = &LB[cur][0];
#pragma unroll
    for (int ks = 0; ks < 2; ++ks) {
      const int ch = (((ks * 4 + fq) ^ (fr & 7)) << 3);
      bf16x8 af[4], bfv[4];
#pragma unroll
      for (int mf = 0; mf < 4; ++mf)
        af[mf] = *(const bf16x8*)(la + (wrow + mf * 16 + fr) * 64 + ch);
#pragma unroll
      for (int nf = 0; nf < 4; ++nf)
        bfv[nf] = *(const bf16x8*)(lb + (wcol + nf * 16 + fr) * 64 + ch);
#pragma unroll
      for (int mf = 0; mf < 4; ++mf)
#pragma unroll
        for (int nf = 0; nf < 4; ++nf)
          acc[mf][nf] = __builtin_amdgcn_mfma_f32_16x16x32_bf16(af[mf], bfv[nf], acc[mf][nf], 0, 0, 0);
    }
    __syncthreads();
  }

  // fused eo-dot epilogue (f32 pre-rounding elu values)
  float w1[4], w2[4];
#pragma unroll
  for (int nf = 0; nf < 4; ++nf) {
    const int n = n0 + wcol + nf * 16 + fr;
    w1[nf] = wvo[l * 1024 + n];
    w2[nf] = wvo[3072 + l * 1024 + n];
  }
  float* p1 = peo + (((size_t)prob * 16) + bi.x * 2 + (w & 1)) * 1024;
  float* p2 = p1 + 393216;   // 24*16*1024
#pragma unroll
  for (int mf = 0; mf < 4; ++mf)
#pragma unroll
    for (int r = 0; r < 4; ++r) {
      float s1 = 0.f, s2 = 0.f;
#pragma unroll
      for (int nf = 0; nf < 4; ++nf) {
        float v = acc[mf][nf][r];
        v = v > 0.f ? v : (__expf(v) - 1.f);
        s1 = fmaf(v, w1[nf], s1);
        s2 = fmaf(v, w2[nf], s2);
      }
      s1 += __shfl_xor(s1, 1); s1 += __shfl_xor(s1, 2); s1 += __shfl_xor(s1, 4); s1 += __shfl_xor(s1, 8);
      s2 += __shfl_xor(s2, 1); s2 += __shfl_xor(s2, 2); s2 += __shfl_xor(s2, 4); s2 += __shfl_xor(s2, 8);
      if (fr == 0) {
        const int rowloc = m0 + wrow + mf * 16 + fq * 4 + r;
        p1[rowloc] = s1;
        p2[rowloc] = s2;
      }
    }
}

// fallback-path hhat (128^2): writes hh
__global__ __launch_bounds__(256) void k_hhat(const bf16_t* __restrict__ att, const bf16_t* __restrict__ WhT,
                                              bf16_t* __restrict__ hh, int ldh) {
  MM_PROLOGUE();
  const int3 bi = xswz3();
  const int m0 = bi.y * 128, n0 = bi.x * 128;
  const int prob = bi.z;
  const int l = prob >> 3, bz = prob & 7;
  const size_t off = ((size_t)prob) << 20;
  mm_bf16(att + off, 1024, WhT + off, 1024, 1024, m0, n0, As, Bs, acc);
  MM_EPI_SETUP(m0, n0);
#pragma unroll
  for (int mf = 0; mf < 4; ++mf)
#pragma unroll
    for (int nf = 0; nf < 4; ++nf) {
      const int n = nb + nf * 16 + fr;
#pragma unroll
      for (int r = 0; r < 4; ++r) {
        const int m = mb + mf * 16 + fq * 4 + r;
        float v = acc[mf][nf][r];
        v = v > 0.f ? v : (__expf(v) - 1.f);
        hh[(size_t)((bz << 10) + m) * ldh + l * 1024 + n] = (bf16_t)v;
      }
    }
}

// reduce peo partials -> eo1/eo2 (raw sums; constants added in k_mask)
__global__ __launch_bounds__(256) void k_eored(const float* __restrict__ peo,
                                               float* __restrict__ eo1, float* __restrict__ eo2) {
  const int m = blockIdx.x * 256 + threadIdx.x;   // 0..8191
  const int b = m >> 10, r = m & 1023;
  float s1 = 0.f, s2 = 0.f;
#pragma unroll
  for (int l = 0; l < 3; ++l)
#pragma unroll
    for (int s = 0; s < 16; ++s) {
      const size_t idx = (((size_t)(l * 8 + b)) * 16 + s) * 1024 + r;
      s1 += peo[idx];
      s2 += peo[393216 + idx];
    }
  eo1[m] = s1;
  eo2[m] = s2;
}

__global__ __launch_bounds__(256) void k_lin(const bf16_t* __restrict__ A, int lda,
                                             const bf16_t* __restrict__ B, int K,
                                             const float* __restrict__ bias, float* __restrict__ out) {
  MM_PROLOGUE();
  const int3 bi = xswz3();
  const int m0 = bi.y * 128, n0 = bi.x * 128;
  mm_bf16(A, lda, B, K, K, m0, n0, As, Bs, acc);
  MM_EPI_SETUP(m0, n0);
#pragma unroll
  for (int mf = 0; mf < 4; ++mf)
#pragma unroll
    for (int nf = 0; nf < 4; ++nf) {
      const int n = nb + nf * 16 + fr;
#pragma unroll
      for (int r = 0; r < 4; ++r) {
        const int m = mb + mf * 16 + fq * 4 + r;
        out[(size_t)m * 512 + n] = acc[mf][nf][r] + bias[n];
      }
    }
}

// fallback: Who (+)= hh @ out_W[:, l*1024:+1024].T (bias folded at l==0)
__global__ __launch_bounds__(256) void k_who_acc(const bf16_t* __restrict__ hh, const bf16_t* __restrict__ Wl,
                                                 const float* __restrict__ Wb, float* __restrict__ Who, int l) {
  MM_PROLOGUE();
  const int m0 = blockIdx.y * 128, n0 = blockIdx.x * 128;
  mm_bf16(hh, 1024, Wl, 3072, 1024, m0, n0, As, Bs, acc);
  MM_EPI_SETUP(m0, n0);
#pragma unroll
  for (int mf = 0; mf < 4; ++mf)
#pragma unroll
    for (int nf = 0; nf < 4; ++nf) {
      const int n = nb + nf * 16 + fr;
#pragma unroll
      for (int r = 0; r < 4; ++r) {
        const int m = mb + mf * 16 + fq * 4 + r;
        const size_t idx = (size_t)m * 512 + n;
        Who[idx] = acc[mf][nf][r] + (l == 0 ? Wb[n] : Who[idx]);
      }
    }
}

// ---------------- fused casts f32 -> bf16 (5 segments) ----------------
__global__ __launch_bounds__(256) void k_cast5(const float* __restrict__ s0, bf16_t* __restrict__ d0, int c0,
                                               const float* __restrict__ s1, bf16_t* __restrict__ d1, int c1,
                                               const float* __restrict__ s2, bf16_t* __restrict__ d2, int c2,
                                               const float* __restrict__ s3, bf16_t* __restrict__ d3, int c3,
                                               const float* __restrict__ s4, bf16_t* __restrict__ d4, int c4) {
  int i = blockIdx.x * 256 + threadIdx.x;
  const float* src; bf16_t* dst; int j;
  if (i < c0)      { src = s0; dst = d0; j = i; }
  else if (i < c1) { src = s1; dst = d1; j = i - c0; }
  else if (i < c2) { src = s2; dst = d2; j = i - c1; }
  else if (i < c3) { src = s3; dst = d3; j = i - c2; }
  else if (i < c4) { src = s4; dst = d4; j = i - c3; }
  else return;
  float4 v = ((const float4*)src)[j];
  union { ushort4 u; bf16_t b[4]; } p;
  p.b[0] = (bf16_t)v.x; p.b[1] = (bf16_t)v.y; p.b[2] = (bf16_t)v.z; p.b[3] = (bf16_t)v.w;
  ((ushort4*)dst)[j] = p.u;
}

// ---------------- x transpose: xbT[b][d][tok] = xb[b][tok][d] ----------------
__global__ __launch_bounds__(256) void k_xt(const bf16_t* __restrict__ in, bf16_t* __restrict__ out) {
  __shared__ bf16_t T[64][72];
  const int t0 = blockIdx.x * 64, d0 = blockIdx.y * 64, b = blockIdx.z;
  const bf16_t* src = in + (size_t)b * 524288;
  bf16_t* dst = out + (size_t)b * 524288;
  const int r = threadIdx.x >> 2, c = (threadIdx.x & 3) * 16;
  bf16x8 a0 = *(const bf16x8*)(src + (size_t)(t0 + r) * 512 + d0 + c);
  bf16x8 a1 = *(const bf16x8*)(src + (size_t)(t0 + r) * 512 + d0 + c + 8);
  *(bf16x8*)&T[r][c] = a0;
  *(bf16x8*)&T[r][c + 8] = a1;
  __syncthreads();
  union { bf16x8 v[2]; bf16_t e[16]; } o;
#pragma unroll
  for (int j = 0; j < 16; ++j) o.e[j] = T[c + j][r];
  *(bf16x8*)(dst + (size_t)(d0 + r) * 1024 + t0 + c) = o.v[0];
  *(bf16x8*)(dst + (size_t)(d0 + r) * 1024 + t0 + c + 8) = o.v[1];
}

// ---------------- algebraic e1/e2 (gat layers) ----------------
__global__ __launch_bounds__(256) void k_wvec(const bf16_t* __restrict__ gatwb,
                                              const float* __restrict__ gWb,
                                              const float* __restrict__ ai, const float* __restrict__ aib,
                                              const float* __restrict__ aj, const float* __restrict__ ajb,
                                              float* __restrict__ wv, float* __restrict__ con) {
  __shared__ float sred[4][64];
  __shared__ float cred[256];
  const int v = blockIdx.y, l = v >> 1;
  const float* avec = ((v & 1) ? aj : ai) + (l << 10);
  const bf16_t* W = gatwb + ((size_t)(l << 10)) * 512;
  const int tid = threadIdx.x, hg = tid >> 6, cc = tid & 63;
  const int c = blockIdx.x * 64 + cc;
  float p = 0.f;
  for (int i = 0; i < 256; ++i) {
    const int h = hg * 256 + i;
    p = fmaf((float)W[(size_t)h * 512 + c], avec[h], p);
  }
  sred[hg][cc] = p;
  float cp = 0.f;
#pragma unroll
  for (int i = 0; i < 4; ++i) cp = fmaf(gWb[(l << 10) + tid + i * 256], avec[tid + i * 256], cp);
  cred[tid] = cp;
  __syncthreads();
  if (tid < 64) wv[v * 512 + blockIdx.x * 64 + tid] = sred[0][tid] + sred[1][tid] + sred[2][tid] + sred[3][tid];
  for (int s = 128; s > 0; s >>= 1) {
    if (tid < s) cred[tid] += cred[tid + s];
    __syncthreads();
  }
  if (tid == 0 && blockIdx.x == 0) con[v] = cred[0] + ((v & 1) ? ajb[l] : aib[l]);
}

// out-attention vectors: wvo[v][c] = sum_d out_W[d][c]*avec[d]; conO[v] = dot(out_Wb, avec).
__global__ __launch_bounds__(256) void k_wvec_o(const float* __restrict__ W, const float* __restrict__ Wb,
                                                const float* __restrict__ ai, const float* __restrict__ aj,
                                                float* __restrict__ wvo, float* __restrict__ conO) {
  const int c = blockIdx.x * 256 + threadIdx.x;     // 0..3071
  const int d0 = blockIdx.y * 64;                   // 8 chunks of 64
  float s1 = 0.f, s2 = 0.f;
  for (int t = 0; t < 64; ++t) {
    const float w = W[(size_t)(d0 + t) * 3072 + c];
    s1 = fmaf(w, ai[d0 + t], s1);
    s2 = fmaf(w, aj[d0 + t], s2);
  }
  atomicAdd(&wvo[c], s1);
  atomicAdd(&wvo[3072 + c], s2);
  if (blockIdx.x == 0 && threadIdx.x < 64) {
    const int d = d0 + threadIdx.x;
    float c1 = Wb[d] * ai[d], c2 = Wb[d] * aj[d];
#pragma unroll
    for (int off = 32; off > 0; off >>= 1) { c1 += __shfl_xor(c1, off); c2 += __shfl_xor(c2, off); }
    if (threadIdx.x == 0) { atomicAdd(&conO[0], c1); atomicAdd(&conO[1], c2); }
  }
}

__global__ __launch_bounds__(256) void k_e12v(const bf16_t* __restrict__ xb,
                                              const float* __restrict__ wv, const float* __restrict__ con,
                                              float* __restrict__ ev) {
  const int tid = threadIdx.x, lane = tid & 63, wid = tid >> 6;
  const int row = blockIdx.x * 4 + wid;
  bf16x8 xv = *(const bf16x8*)(xb + (size_t)row * 512 + lane * 8);
  float xf[8];
#pragma unroll
  for (int j = 0; j < 8; ++j) xf[j] = (float)xv[j];
  float s[6];
#pragma unroll
  for (int v = 0; v < 6; ++v) {
    const float* wp = wv + v * 512 + lane * 8;
    float a = 0.f;
#pragma unroll
    for (int j = 0; j < 8; ++j) a = fmaf(xf[j], wp[j], a);
    s[v] = a;
  }
#pragma unroll
  for (int v = 0; v < 6; ++v)
#pragma unroll
    for (int off = 32; off > 0; off >>= 1) s[v] += __shfl_xor(s[v], off);
  if (lane == 0) {
#pragma unroll
    for (int v = 0; v < 6; ++v) ev[v * 8192 + row] = s[v] + con[v];
  }
}

// fallback: raw row-dots (constants added in k_mask)
__global__ __launch_bounds__(256) void k_eo(const float* __restrict__ Who,
                                            const float* __restrict__ ai, const float* __restrict__ aj,
                                            float* __restrict__ eo1, float* __restrict__ eo2) {
  const int wid = threadIdx.x >> 6, lane = threadIdx.x & 63;
  const int row = blockIdx.x * 4 + wid;
  const float* wr = Who + (size_t)row * 512;
  float s1 = 0.f, s2 = 0.f;
#pragma unroll
  for (int c = 0; c < 2; ++c) {
    const int idx = c * 256 + lane * 4;
    float4 w4 = *(const float4*)&wr[idx];
    float4 a4 = *(const float4*)&ai[idx];
    float4 b4 = *(const float4*)&aj[idx];
    s1 += w4.x * a4.x + w4.y * a4.y + w4.z * a4.z + w4.w * a4.w;
    s2 += w4.x * b4.x + w4.y * b4.y + w4.z * b4.z + w4.w * b4.w;
  }
#pragma unroll
  for (int off = 32; off > 0; off >>= 1) { s1 += __shfl_xor(s1, off); s2 += __shfl_xor(s2, off); }
  if (lane == 0) { eo1[row] = s1; eo2[row] = s2; }
}

// ---------------- block reduce helpers (fallback kernels) ----------------
__device__ __forceinline__ float block_max(float v, float* red) {
#pragma unroll
  for (int off = 32; off > 0; off >>= 1) v = fmaxf(v, __shfl_xor(v, off));
  __syncthreads();
  if ((threadIdx.x & 63) == 0) red[threadIdx.x >> 6] = v;
  __syncthreads();
  return fmaxf(fmaxf(red[0], red[1]), fmaxf(red[2], red[3]));
}
__device__ __forceinline__ float block_sum(float v, float* red) {
#pragma unroll
  for (int off = 32; off > 0; off >>= 1) v += __shfl_xor(v, off);
  __syncthreads();
  if ((threadIdx.x & 63) == 0) red[threadIdx.x >> 6] = v;
  __syncthreads();
  return red[0] + red[1] + red[2] + red[3];
}

// ---------------- GAT attention rows: wave-per-row, all 3 layers, no barriers ----------------
__global__ __launch_bounds__(256) void k_gat_att3(const float* __restrict__ adj, const float* __restrict__ ev,
                                                  bf16_t* __restrict__ att) {
  const int lane = threadIdx.x & 63;
  const int row = blockIdx.x * 4 + (threadIdx.x >> 6);
  const int b = row >> 10;
  const float* arow = adj + (size_t)row * 1024;
  float a[4][4];
#pragma unroll
  for (int c = 0; c < 4; ++c) *(float4*)a[c] = *(const float4*)&arow[(c * 64 + lane) * 4];
#pragma unroll
  for (int l = 0; l < 3; ++l) {
    const float e1v = ev[l * 16384 + row];
    const float* e2r = ev + l * 16384 + 8192 + (b << 10);
    bf16_t* aout = att + (size_t)l * 8388608 + (size_t)row * 1024;
    float s[4][4];
    float mx = -1e30f;
#pragma unroll
    for (int c = 0; c < 4; ++c) {
      float4 e4 = *(const float4*)&e2r[(c * 64 + lane) * 4];
      float ee[4] = {e4.x, e4.y, e4.z, e4.w};
#pragma unroll
      for (int j = 0; j < 4; ++j) {
        float e = e1v + ee[j];
        e = e > 0.f ? e : 0.2f * e;
        s[c][j] = a[c][j] * e;
        mx = fmaxf(mx, s[c][j]);
      }
    }
#pragma unroll
    for (int off = 32; off > 0; off >>= 1) mx = fmaxf(mx, __shfl_xor(mx, off));
    float sum = 0.f;
#pragma unroll
    for (int c = 0; c < 4; ++c)
#pragma unroll
      for (int j = 0; j < 4; ++j) { float p = __expf(s[c][j] - mx); s[c][j] = p; sum += p; }
#pragma unroll
    for (int off = 32; off > 0; off >>= 1) sum += __shfl_xor(sum, off);
    const float inv = 1.f / sum;
#pragma unroll
    for (int c = 0; c < 4; ++c) {
      union { ushort4 u; bf16_t q[4]; } pk;
#pragma unroll
      for (int j = 0; j < 4; ++j) pk.q[j] = (bf16_t)(s[c][j] * inv);
      *(ushort4*)(aout + (c * 64 + lane) * 4) = pk.u;
    }
  }
}

// fallback single-layer version (block-per-row)
__global__ __launch_bounds__(256) void k_gat_att(const float* __restrict__ adj, const float* __restrict__ ev,
                                                 bf16_t* __restrict__ att) {
  __shared__ float red[4];
  const int row = blockIdx.x;
  const int b = row >> 10;
  const float* arow = adj + (size_t)row * 1024;
  const float e1v = ev[row];
  const float* e2r = ev + 8192 + (b << 10);
  float s[4];
  float mx = -1e30f;
#pragma unroll
  for (int c = 0; c < 4; ++c) {
    const int m = c * 256 + threadIdx.x;
    float e = e1v + e2r[m];
    e = e > 0.f ? e : 0.2f * e;
    s[c] = arow[m] * e;
    mx = fmaxf(mx, s[c]);
  }
  mx = block_max(mx, red);
  float sum = 0.f;
#pragma unroll
  for (int c = 0; c < 4; ++c) { float p = __expf(s[c] - mx); s[c] = p; sum += p; }
  sum = block_sum(sum, red);
  const float inv = 1.f / sum;
#pragma unroll
  for (int c = 0; c < 4; ++c) att[(size_t)row * 1024 + c * 256 + threadIdx.x] = (bf16_t)(s[c] * inv);
}

// ---------------- output-attention mask: wave-per-row double softmax ----------------
__global__ __launch_bounds__(256) void k_mask(const float* __restrict__ adj, const float* __restrict__ eo1,
                                              const float* __restrict__ eo2, const float* __restrict__ conO,
                                              const float* __restrict__ aib, const float* __restrict__ ajb,
                                              bf16_t* __restrict__ mask) {
  const int lane = threadIdx.x & 63;
  const int row = blockIdx.x * 4 + (threadIdx.x >> 6);
  const int b = row >> 10;
  const float* arow = adj + (size_t)row * 1024;
  const float t1 = eo1[row] + conO[0] + aib[0];
  const float c2 = conO[1] + ajb[0];
  const float* eor = eo2 + (b << 10);
  float s[4][4];
  float mx = -1e30f;
#pragma unroll
  for (int c = 0; c < 4; ++c) {
    float4 a4 = *(const float4*)&arow[(c * 64 + lane) * 4];
    float4 e4 = *(const float4*)&eor[(c * 64 + lane) * 4];
    float aa[4] = {a4.x, a4.y, a4.z, a4.w};
    float ee[4] = {e4.x, e4.y, e4.z, e4.w};
#pragma unroll
    for (int j = 0; j < 4; ++j) {
      float e = t1 + ee[j] + c2;
      e = e > 0.f ? e : 0.2f * e;
      s[c][j] = aa[j] * e;
      mx = fmaxf(mx, s[c][j]);
    }
  }
#pragma unroll
  for (int off = 32; off > 0; off >>= 1) mx = fmaxf(mx, __shfl_xor(mx, off));
  float sum = 0.f;
#pragma unroll
  for (int c = 0; c < 4; ++c)
#pragma unroll
    for (int j = 0; j < 4; ++j) { float p = __expf(s[c][j] - mx); s[c][j] = p; sum += p; }
#pragma unroll
  for (int off = 32; off > 0; off >>= 1) sum += __shfl_xor(sum, off);
  const float inv = 1.f / sum;        // == max of first softmax
  float sum2 = 0.f;
#pragma unroll
  for (int c = 0; c < 4; ++c)
#pragma unroll
    for (int j = 0; j < 4; ++j) { float p = __expf(s[c][j] * inv - inv); s[c][j] = p; sum2 += p; }
#pragma unroll
  for (int off = 32; off > 0; off >>= 1) sum2 += __shfl_xor(sum2, off);
  const float inv2 = 1.f / sum2;
#pragma unroll
  for (int c = 0; c < 4; ++c) {
    union { ushort4 u; bf16_t q[4]; } pk;
#pragma unroll
    for (int j = 0; j < 4; ++j) pk.q[j] = (bf16_t)(s[c][j] * inv2);
    *(ushort4*)(mask + (size_t)row * 1024 + (c * 64 + lane) * 4) = pk.u;
  }
}

// ---------------- mask transpose ----------------
__global__ __launch_bounds__(256) void k_mtr(const bf16_t* __restrict__ in, bf16_t* __restrict__ out) {
  __shared__ bf16_t T[64][72];
  const int q0 = blockIdx.x * 64, k0 = blockIdx.y * 64, b = blockIdx.z;
  const bf16_t* src = in + ((size_t)b << 20);
  bf16_t* dst = out + ((size_t)b << 20);
  const int r = threadIdx.x >> 2, c = (threadIdx.x & 3) * 16;
  bf16x8 a0 = *(const bf16x8*)(src + (size_t)(q0 + r) * 1024 + k0 + c);
  bf16x8 a1 = *(const bf16x8*)(src + (size_t)(q0 + r) * 1024 + k0 + c + 8);
  *(bf16x8*)&T[r][c] = a0;
  *(bf16x8*)&T[r][c + 8] = a1;
  __syncthreads();
  union { bf16x8 v[2]; bf16_t e[16]; } o;
#pragma unroll
  for (int j = 0; j < 16; ++j) o.e[j] = T[c + j][r];
  *(bf16x8*)(dst + (size_t)(k0 + r) * 1024 + q0 + c) = o.v[0];
  *(bf16x8*)(dst + (size_t)(k0 + r) * 1024 + q0 + c + 8) = o.v[1];
}

// ---------------- MFMA flash attention (XOR-swizzled K/V + P LDS) ----------------
__device__ __forceinline__ int swz(int row, int slot) { return row * 64 + ((slot ^ (row & 7)) << 3); }

__global__ __launch_bounds__(256) void k_flash(const bf16_t* __restrict__ qg, const bf16_t* __restrict__ kg,
                                               const bf16_t* __restrict__ vTg, const bf16_t* __restrict__ maskT,
                                               bf16_t* __restrict__ aout) {
  __shared__ __align__(16) bf16_t Ks[4096];
  __shared__ __align__(16) bf16_t Vs[4096];
  __shared__ __align__(16) bf16_t PL[4][1024];   // per-wave 16x64, swizzled
  const int tid = threadIdx.x, lane = tid & 63, w = tid >> 6;
  const int fr = lane & 15, fq = lane >> 4;
  const int3 bi = xswz3();
  const int n0 = bi.x * 64, hh = bi.y, bb = bi.z;
  const size_t bh = ((size_t)bb * 8 + hh) << 16;
  const bf16_t* q = qg + bh;
  const bf16_t* kk = kg + bh;
  const bf16_t* vT = vTg + bh;
  const bf16_t* mT = maskT + ((size_t)bb << 20);
  bf16_t* PLw = &PL[w][0];

  bf16x8 qf[2];
#pragma unroll
  for (int ks = 0; ks < 2; ++ks)
    qf[ks] = *(const bf16x8*)(q + (size_t)(n0 + w * 16 + fr) * 64 + ks * 32 + fq * 8);

  f32x4 o[4];
#pragma unroll
  for (int nf = 0; nf < 4; ++nf) o[nf] = (f32x4)0.0f;
  float psum[4] = {0.f, 0.f, 0.f, 0.f};

  const int srow = tid >> 2, sslot = (tid & 3) * 2;
  const int ws0 = swz(srow, sslot), ws1 = swz(srow, sslot + 1);
  const int scol = (tid & 3) * 16;

  for (int c = 0; c < 16; ++c) {
    const int k0 = c * 64;
    bf16x8 kv0 = *(const bf16x8*)(kk + (size_t)(k0 + srow) * 64 + scol);
    bf16x8 kv1 = *(const bf16x8*)(kk + (size_t)(k0 + srow) * 64 + scol + 8);
    bf16x8 vv0 = *(const bf16x8*)(vT + (size_t)srow * 1024 + k0 + scol);
    bf16x8 vv1 = *(const bf16x8*)(vT + (size_t)srow * 1024 + k0 + scol + 8);
    union { ushort4 u; bf16_t h[4]; } mfr[4];
#pragma unroll
    for (int nf = 0; nf < 4; ++nf)
      mfr[nf].u = *(const ushort4*)(mT + (size_t)(k0 + nf * 16 + fr) * 1024 + n0 + w * 16 + fq * 4);
    __syncthreads();
    *(bf16x8*)&Ks[ws0] = kv0; *(bf16x8*)&Ks[ws1] = kv1;
    *(bf16x8*)&Vs[ws0] = vv0; *(bf16x8*)&Vs[ws1] = vv1;
    __syncthreads();

    f32x4 s[4];
#pragma unroll
    for (int nf = 0; nf < 4; ++nf) s[nf] = (f32x4)0.0f;
#pragma unroll
    for (int ks = 0; ks < 2; ++ks) {
      bf16x8 kf[4];
#pragma unroll
      for (int nf = 0; nf < 4; ++nf)
        kf[nf] = *(const bf16x8*)&Ks[swz(nf * 16 + fr, ks * 4 + fq)];
#pragma unroll
      for (int nf = 0; nf < 4; ++nf)
        s[nf] = __builtin_amdgcn_mfma_f32_16x16x32_bf16(qf[ks], kf[nf], s[nf], 0, 0, 0);
    }

#pragma unroll
    for (int nf = 0; nf < 4; ++nf)
#pragma unroll
      for (int r = 0; r < 4; ++r) {
        const float p = __expf(s[nf][r] * (float)mfr[nf].h[r]);
        psum[r] += p;
        const int pp = fq * 4 + r, e = nf * 16 + fr;
        PLw[pp * 64 + ((((e >> 3) ^ (pp & 7))) << 3) + (e & 7)] = (bf16_t)p;
      }

#pragma unroll
    for (int ks = 0; ks < 2; ++ks) {
      bf16x8 pf = *(const bf16x8*)&PLw[swz(fr, ks * 4 + fq)];
      bf16x8 vf[4];
#pragma unroll
      for (int nfo = 0; nfo < 4; ++nfo)
        vf[nfo] = *(const bf16x8*)&Vs[swz(nfo * 16 + fr, ks * 4 + fq)];
#pragma unroll
      for (int nfo = 0; nfo < 4; ++nfo)
        o[nfo] = __builtin_amdgcn_mfma_f32_16x16x32_bf16(pf, vf[nfo], o[nfo], 0, 0, 0);
    }
  }

#pragma unroll
  for (int r = 0; r < 4; ++r) {
    psum[r] += __shfl_xor(psum[r], 1);
    psum[r] += __shfl_xor(psum[r], 2);
    psum[r] += __shfl_xor(psum[r], 4);
    psum[r] += __shfl_xor(psum[r], 8);
  }
#pragma unroll
  for (int r = 0; r < 4; ++r) {
    const int tok = n0 + w * 16 + fq * 4 + r;
    const float inv = 1.f / psum[r];
#pragma unroll
    for (int nfo = 0; nfo < 4; ++nfo)
      aout[((size_t)(bb << 10) + tok) * 512 + hh * 64 + nfo * 16 + fr] = (bf16_t)(o[nfo][r] * inv);
  }
}

// ---------------- launcher ----------------
extern "C" void kernel_launch(void* const* d_in, const int* in_sizes, int n_in,
                              void* d_out, int out_size, void* d_ws, size_t ws_size,
                              hipStream_t stream) {
  (void)in_sizes; (void)n_in; (void)out_size;
  const float* x        = (const float*)d_in[0];
  const float* adj      = (const float*)d_in[1];
  const float* qkv_w    = (const float*)d_in[2];
  const float* proj_w   = (const float*)d_in[3];
  const float* proj_b   = (const float*)d_in[4];
  const float* gat_W    = (const float*)d_in[5];
  const float* gat_Wb   = (const float*)d_in[6];
  const float* gat_ai   = (const float*)d_in[7];
  const float* gat_ai_b = (const float*)d_in[8];
  const float* gat_aj   = (const float*)d_in[9];
  const float* gat_aj_b = (const float*)d_in[10];
  const float* out_W    = (const float*)d_in[11];
  const float* out_Wb   = (const float*)d_in[12];
  const float* out_ai   = (const float*)d_in[13];
  const float* out_ai_b = (const float*)d_in[14];
  const float* out_aj   = (const float*)d_in[15];
  const float* out_aj_b = (const float*)d_in[16];

  char* p = (char*)d_ws;
  auto alloc = [&](size_t bytes) { char* r = p; p += (bytes + 255) & ~(size_t)255; return r; };
  bf16_t* xb     = (bf16_t*)alloc(8192ull * 512 * 2);
  bf16_t* qkvwb  = (bf16_t*)alloc(1536ull * 512 * 2);
  bf16_t* gatwb  = (bf16_t*)alloc(3072ull * 512 * 2);
  bf16_t* outwb  = (bf16_t*)alloc(512ull * 3072 * 2);
  bf16_t* projwb = (bf16_t*)alloc(512ull * 512 * 2);
  bf16_t* xbT    = (bf16_t*)alloc(8ull * 512 * 1024 * 2);   // [b][d][tok]
  bf16_t* qb     = (bf16_t*)alloc(8ull * 8 * 1024 * 64 * 2);
  bf16_t* kb     = (bf16_t*)alloc(8ull * 8 * 1024 * 64 * 2);
  bf16_t* vT     = (bf16_t*)alloc(8ull * 8 * 64 * 1024 * 2);
  float*  Who    = (float*)alloc(8192ull * 512 * 4);   // fallback only
  float*  wv     = (float*)alloc(6 * 512 * 4);
  float*  con    = (float*)alloc(256);
  float*  ev     = (float*)alloc(6 * 8192 * 4);
  float*  eo1    = (float*)alloc(8192 * 4);
  float*  eo2    = (float*)alloc(8192 * 4);
  float*  peo    = (float*)alloc(2ull * 393216 * 4);   // [2][24][16][1024] partials
  // zero-init region: wvo, conO (atomic targets)
  float*  wvo    = (float*)alloc(2 * 3072 * 4);
  float*  conO   = (float*)alloc(256);
  const size_t zspan = (size_t)((char*)conO - (char*)wvo) + 256;

  const bool big = ws_size >= 211000000ull;

  const dim3 blk(256);
  k_cast5<<<8192, blk, 0, stream>>>(x, xb, 1048576, qkv_w, qkvwb, 1245184, gat_W, gatwb, 1638400,
                                    out_W, outwb, 2031616, proj_w, projwb, 2097152);
  hipMemsetAsync(wvo, 0, zspan, stream);
  k_wvec<<<dim3(8, 6), blk, 0, stream>>>(gatwb, gat_Wb, gat_ai, gat_ai_b, gat_aj, gat_aj_b, wv, con);
  k_wvec_o<<<dim3(12, 8), blk, 0, stream>>>(out_W, out_Wb, out_ai, out_aj, wvo, conO);
  k_e12v<<<2048, blk, 0, stream>>>(xb, wv, con, ev);
  k_xt<<<dim3(16, 8, 8), blk, 0, stream>>>(xb, xbT);
  k_qkv<<<dim3(12, 64), blk, 0, stream>>>(xb, qkvwb, qb, kb, vT);

  if (big) {
    bf16_t* att3 = (bf16_t*)alloc(3ull * 8 * 1024 * 1024 * 2);
    bf16_t* Y    = (bf16_t*)alloc(24ull * 1024 * 512 * 2);     // [24][1024][512]
    bf16_t* mask  = att3;
    bf16_t* maskT = att3 + 8388608;
    bf16_t* aoutb = att3 + 2 * 8388608;

    k_gat_att3<<<2048, blk, 0, stream>>>(adj, ev, att3);
    k_attx<<<dim3(4, 8, 24), blk, 0, stream>>>(att3, xbT, Y);
    k_hhatB<<<dim3(8, 4, 24), dim3(512), 0, stream>>>(Y, gatwb, wvo, peo);
    k_eored<<<32, blk, 0, stream>>>(peo, eo1, eo2);
    k_mask<<<2048, blk, 0, stream>>>(adj, eo1, eo2, conO, out_ai_b, out_aj_b, mask);
    k_mtr<<<dim3(16, 16, 8), blk, 0, stream>>>(mask, maskT);
    k_flash<<<dim3(16, 8, 8), blk, 0, stream>>>(qb, kb, vT, maskT, aoutb);
    k_lin<<<dim3(4, 64), blk, 0, stream>>>(aoutb, 512, projwb, 512, proj_b, (float*)d_out);
  } else {
    bf16_t* WhT   = (bf16_t*)alloc(8ull * 1024 * 1024 * 2);
    bf16_t* att   = (bf16_t*)alloc(8ull * 1024 * 1024 * 2);
    bf16_t* hh    = (bf16_t*)alloc(8192ull * 1024 * 2);
    bf16_t* aoutb = (bf16_t*)alloc(8192ull * 512 * 2);
    bf16_t* maskT = (bf16_t*)alloc(8ull * 1024 * 1024 * 2);
    bf16_t* mask  = att;

    for (int l = 0; l < 3; ++l) {
      k_wh<<<dim3(8, 64, 1), blk, 0, stream>>>(xb, gatwb + (size_t)l * 524288, gat_Wb + l * 1024, WhT);
      k_gat_att<<<8192, blk, 0, stream>>>(adj, ev + (size_t)l * 16384, att);
      k_hhat<<<dim3(8, 8, 8), blk, 0, stream>>>(att, WhT, hh, 1024);
      k_who_acc<<<dim3(4, 64), blk, 0, stream>>>(hh, outwb + l * 1024, out_Wb, Who, l);
    }
    k_eo<<<2048, blk, 0, stream>>>(Who, out_ai, out_aj, eo1, eo2);
    k_mask<<<2048, blk, 0, stream>>>(adj, eo1, eo2, conO, out_ai_b, out_aj_b, mask);
    k_mtr<<<dim3(16, 16, 8), blk, 0, stream>>>(mask, maskT);
    k_flash<<<dim3(16, 8, 8), blk, 0, stream>>>(qb, kb, vT, maskT, aoutb);
    k_lin<<<dim3(4, 64), blk, 0, stream>>>(aoutb, 512, projwb, 512, proj_b, (float*)d_out);
  }
}